// Round 19
// baseline (717.327 us; speedup 1.0000x reference)
//
#include <hip/hip_runtime.h>
#include <math.h>

#define NTOK 32768
#define DIM 256
#define KCB 8192
#define RESCUE_TAU 4e-3f

typedef _Float16 half8 __attribute__((ext_vector_type(8)));
typedef float f32x4 __attribute__((ext_vector_type(4)));
typedef unsigned long long u64;
typedef unsigned int u32;

// ---------------- fast-path ws layout (bytes) ----------------
#define OFF_AN    0ull
#define OFF_CN    131072ull
#define OFF_IDS   163840ull
#define OFF_RCNT  294912ull
#define OFF_RLIST 295040ull
#define OFF_PART  426112ull      // 2048 doubles
#define OFF_PK1   442496ull      // u64 [32768][8]; first 256KB reused as rmin[]
#define OFF_PV2   2539648ull     // f32 [32768][8]
#define OFF_Z16   3588224ull     // [256 tile][8 ks][128 row][64 halves swz]
#define OFF_CB16  37142656ull    // cb16h: [32 tile][8 ks][256 row][32 halves swz]
#define WS_NEED   45531264ull

#define GLOAD_LDS16(gp, lp) __builtin_amdgcn_global_load_lds( \
    (const __attribute__((address_space(1))) void*)(gp), \
    (__attribute__((address_space(3))) void*)(lp), 16, 0, 0)

static __device__ __forceinline__ u64 umin64(u64 a, u64 b) { return a < b ? a : b; }
static __device__ __forceinline__ u64 umax64(u64 a, u64 b) { return a < b ? b : a; }

// ---- numpy-pairwise ||row||^2 (bitwise-matching np.sum(x*x,axis=1)) ------
__global__ __launch_bounds__(256)
void rownorm256_np(const float* __restrict__ M, float* __restrict__ out, int rows) {
  int r = blockIdx.x * 256 + threadIdx.x;
  if (r >= rows) return;
  const float* p = M + (size_t)r * DIM;
  float blk[2];
#pragma unroll
  for (int b = 0; b < 2; ++b) {
    const float* a = p + b * 128;
    float rr[8];
#pragma unroll
    for (int j = 0; j < 8; ++j) rr[j] = __fmul_rn(a[j], a[j]);
    for (int i = 8; i < 128; i += 8) {
#pragma unroll
      for (int j = 0; j < 8; ++j)
        rr[j] = __fadd_rn(rr[j], __fmul_rn(a[i + j], a[i + j]));
    }
    float s01 = __fadd_rn(rr[0], rr[1]);
    float s23 = __fadd_rn(rr[2], rr[3]);
    float s45 = __fadd_rn(rr[4], rr[5]);
    float s67 = __fadd_rn(rr[6], rr[7]);
    blk[b] = __fadd_rn(__fadd_rn(s01, s23), __fadd_rn(s45, s67));
  }
  out[r] = __fadd_rn(blk[0], blk[1]);
}

// ---- convert z: fp32 -> scaled fp16 (hi,lo) pair, pre-swizzled (UNCHANGED) --
__global__ __launch_bounds__(128)
void conv_z16(const float* __restrict__ z, _Float16* __restrict__ dst) {
  const int tile = blockIdx.x >> 3, ks = blockIdx.x & 7, row = threadIdx.x;
  const float* src = z + ((size_t)(tile * 128 + row)) * DIM + ks * 32;
  _Float16* d = dst + (u64)tile * 65536 + (u64)ks * 8192 + row * 64;
  const int rs = row & 7;
#pragma unroll
  for (int q = 0; q < 4; ++q) {
    half8 hv, lv;
#pragma unroll
    for (int j = 0; j < 8; ++j) {
      float f = src[q * 8 + j] * 64.0f;          // exact pow2 scale
      _Float16 h = (_Float16)f;                  // RNE
      float lf = f - (float)h;                   // exact
      hv[j] = h; lv[j] = (_Float16)lf;
    }
    *reinterpret_cast<half8*>(d + ((q ^ rs) * 8)) = hv;
    *reinterpret_cast<half8*>(d + (((q + 4) ^ rs) * 8)) = lv;
  }
}

// ---- convert cb: HI PLANE ONLY, compact rows of 32 halves ----------------
// layout: cb16h[tile*65536 + ks*8192 + row*32 + (q ^ (row&3))*8 + j]
__global__ __launch_bounds__(256)
void conv_cb16h(const float* __restrict__ cb, _Float16* __restrict__ dst) {
  const int tile = blockIdx.x >> 3, ks = blockIdx.x & 7, row = threadIdx.x;
  const float* src = cb + ((size_t)(tile * 256 + row)) * DIM + ks * 32;
  _Float16* d = dst + (u64)tile * 65536 + (u64)ks * 8192 + row * 32;
  const int rs = row & 3;
#pragma unroll
  for (int q = 0; q < 4; ++q) {
    half8 hv;
#pragma unroll
    for (int j = 0; j < 8; ++j) {
      float f = src[q * 8 + j] * 1024.0f;        // exact pow2 scale
      hv[j] = (_Float16)f;                       // RNE hi
    }
    *reinterpret_cast<half8*>(d + ((q ^ rs) * 8)) = hv;
  }
}

// ---- MFMA GEMM + per-LANE top-2: A(hi+lo) in regs, B hi-only via LDS -----
// Block: 64 tokens x 128 codes, 4 waves (2m x 2n), wave-tile 32x64.
// Split: dot ~= (zh+zl)*ch; dropped z''*cl has 6-sigma ~8.4e-4 << TAU/2.
// R18 BUG FIXED: global_load_lds writes lane-linear (base + lane*16B);
// STAGE_B must give each instruction a 16B/lane-stride dest. We stage the
// 8KB tile as two 4KB chunks, each linear across the 256 threads (R17
// pattern), NOT per-thread 32B segments (R18's corruption).
__global__ __launch_bounds__(256, 3)
void vq_mfma_top2(const _Float16* __restrict__ z16, const _Float16* __restrict__ cb16h,
                  const float* __restrict__ An, const float* __restrict__ Cn,
                  u64* __restrict__ pk1, float* __restrict__ pv2) {
  __shared__ _Float16 Bs0[128 * 32];   // 8 KB
  __shared__ _Float16 Bs1[128 * 32];   // 8 KB
  __shared__ float    Cs[1024];        // 4 KB  (this cg's code norms)
  __shared__ u64      t2k[64][2];      // 1 KB
  __shared__ u32      t2v[64][2];      // 0.5 KB

  const int tid = threadIdx.x;
  const int lane = tid & 63, w = tid >> 6;
  const int wm = w >> 1, wn = w & 1;
  // XCD swizzle: grid 4096, 8 XCDs -> each XCD owns exactly one cgroup
  const int swz = (blockIdx.x & 7) * 512 + (blockIdx.x >> 3);
  const int cg = swz >> 9, rem = swz & 511;
  const int ttile = rem >> 1, thalf = rem & 1;
  const int laneM = lane & 15, laneK = lane >> 4;
  const _Float16* zt = z16 + (u64)ttile * 65536;

  // A-fragment per-lane offsets: hi plane [0..1], lo plane [2..3] (R13 formula)
  int offA[4];
#pragma unroll
  for (int f = 0; f < 2; ++f) {
    int row = thalf * 64 + wm * 32 + f * 16 + laneM;
    offA[f]     = row * 64 + ((laneK ^ (row & 7)) * 8);
    offA[f + 2] = row * 64 + (((laneK + 4) ^ (row & 7)) * 8);
  }
  // B-fragment offsets in the compact 32-half rows (granule = laneK^(row&3))
  int offBh[4];
#pragma unroll
  for (int g = 0; g < 4; ++g) {
    int row = wn * 64 + g * 16 + laneM;
    offBh[g] = row * 32 + ((laneK ^ (row & 3)) * 8);
  }

  // preload A hi+lo fragments (8 ks x 4 half8) -> registers, once
  half8 Ah[8][4];
#pragma unroll
  for (int ks = 0; ks < 8; ++ks)
#pragma unroll
    for (int f = 0; f < 4; ++f)
      Ah[ks][f] = *reinterpret_cast<const half8*>(zt + ks * 8192 + offA[f]);

  // token norms
  float Areg[2][4];
#pragma unroll
  for (int f = 0; f < 2; ++f) {
    float4 a4 = *reinterpret_cast<const float4*>(
        &An[ttile * 128 + thalf * 64 + wm * 32 + f * 16 + laneK * 4]);
    Areg[f][0] = a4.x; Areg[f][1] = a4.y; Areg[f][2] = a4.z; Areg[f][3] = a4.w;
  }
  {  // stage this cg's code norms into LDS
    float4 c4 = *reinterpret_cast<const float4*>(&Cn[cg * 1024 + tid * 4]);
    *reinterpret_cast<float4*>(&Cs[tid * 4]) = c4;
  }

  // per-lane top-2 state: 8 token-slots
  u32 v1b[8], v2b[8], c1v[8];
#pragma unroll
  for (int s = 0; s < 8; ++s) { v1b[s] = 0x7F800000u; v2b[s] = 0x7F800000u; c1v[s] = 0; }
  u32 codeSub = (u32)(cg * 1024 + wn * 64 + laneM);  // += 128 per sub

// stage one 128-code hi-plane tile (8KB) as TWO lane-linear 4KB chunks:
// chunk c covers halves [c*2048, c*2048+2048), thread tid -> 8 halves at
// c*2048 + tid*8 (16B per lane per instruction => stride == width, valid)
#define STAGE_B(s, Bd) do {                                                  \
    const int ns_ = (s) >> 3, nk_ = (s) & 7;                                 \
    const _Float16* sb_ = cb16h + (u64)(cg * 4 + (ns_ >> 1)) * 65536 +       \
                          (u64)nk_ * 8192 + (u64)(ns_ & 1) * 4096 + tid * 8; \
    GLOAD_LDS16(sb_,        &Bd[tid * 8]);                                   \
    GLOAD_LDS16(sb_ + 2048, &Bd[tid * 8 + 2048]);                            \
  } while (0)

// 2-pass on A: AhHi x bh + AhLo x bh  (16 MFMA per step, B read once)
#define COMPUTE_KS(kc, Bsrc) do {                                            \
    _Pragma("unroll")                                                        \
    for (int g_ = 0; g_ < 4; ++g_) {                                         \
      half8 bh = *reinterpret_cast<const half8*>(&Bsrc[offBh[g_]]);          \
      _Pragma("unroll")                                                      \
      for (int f_ = 0; f_ < 2; ++f_)                                         \
        acc[f_][g_] = __builtin_amdgcn_mfma_f32_16x16x32_f16(Ah[kc][f_], bh, acc[f_][g_], 0, 0, 0);     \
      _Pragma("unroll")                                                      \
      for (int f_ = 0; f_ < 2; ++f_)                                         \
        acc[f_][g_] = __builtin_amdgcn_mfma_f32_16x16x32_f16(Ah[kc][f_ + 2], bh, acc[f_][g_], 0, 0, 0); \
    }                                                                        \
  } while (0)

  // prologue: stage step 0 into Bs0
  STAGE_B(0, Bs0);
  __syncthreads();   // Bs0 + Cs ready

  f32x4 acc[2][4];
#pragma unroll
  for (int f = 0; f < 2; ++f)
#pragma unroll
    for (int g = 0; g < 4; ++g) acc[f][g] = (f32x4){0.f, 0.f, 0.f, 0.f};

  for (int sub = 0; sub < 8; ++sub) {
#pragma unroll
    for (int ks = 0; ks < 8; ++ks) {
      const int step = sub * 8 + ks;
      if (step < 63) {
        if (ks & 1) STAGE_B(step + 1, Bs0);
        else        STAGE_B(step + 1, Bs1);
      }
      if (ks & 1) COMPUTE_KS(ks, Bs1);
      else        COMPUTE_KS(ks, Bs0);

      if (ks == 7) {  // sub complete: per-lane top-2 update
        const int cbase = sub * 128 + wn * 64 + laneM;
        float Cg[4];
#pragma unroll
        for (int g = 0; g < 4; ++g) Cg[g] = Cs[cbase + g * 16];
#pragma unroll
        for (int f = 0; f < 2; ++f) {
#pragma unroll
          for (int r = 0; r < 4; ++r) {
            const int sl = f * 4 + r;
            const float Ar = Areg[f][r];
#pragma unroll
            for (int g = 0; g < 4; ++g) {
              float p2 = __fmul_rn(acc[f][g][r], 0x1p-15f);   // 2*dot, exact pow2
              float t1 = __fsub_rn(Ar, p2);
              float t  = __fadd_rn(t1, Cg[g]);
              u32 tb = __float_as_uint(t);        // t>0 -> bit cmp == float cmp
              u32 code = codeSub + (u32)(g * 16);
              bool lt1 = tb < v1b[sl];
              bool lt2 = tb < v2b[sl];
              v2b[sl] = lt1 ? v1b[sl] : (lt2 ? tb : v2b[sl]);
              c1v[sl] = lt1 ? code : c1v[sl];
              v1b[sl] = lt1 ? tb : v1b[sl];
            }
          }
        }
        codeSub += 128;
#pragma unroll
        for (int f = 0; f < 2; ++f)
#pragma unroll
          for (int g = 0; g < 4; ++g) acc[f][g] = (f32x4){0.f, 0.f, 0.f, 0.f};
      }
      __syncthreads();   // staged buffer ready; all waves done reading cur
    }
  }

#undef STAGE_B
#undef COMPUTE_KS

  // final cross-lane (laneM) top-2 reduce, once per kernel
#pragma unroll
  for (int sl = 0; sl < 8; ++sl) {
#pragma unroll
    for (int d = 1; d < 16; d <<= 1) {
      u32 o1 = (u32)__shfl_xor((int)v1b[sl], d);
      u32 oc = (u32)__shfl_xor((int)c1v[sl], d);
      u32 o2 = (u32)__shfl_xor((int)v2b[sl], d);
      u64 k  = ((u64)v1b[sl] << 32) | c1v[sl];
      u64 ko = ((u64)o1 << 32) | oc;
      u32 loser = v1b[sl] < o1 ? o1 : v1b[sl];
      u32 nv2 = min(loser, min(v2b[sl], o2));
      u64 nk = umin64(k, ko);
      v1b[sl] = (u32)(nk >> 32); c1v[sl] = (u32)nk; v2b[sl] = nv2;
    }
  }
  if (laneM == 0) {
#pragma unroll
    for (int f = 0; f < 2; ++f)
#pragma unroll
      for (int r = 0; r < 4; ++r) {
        const int tloc = wm * 32 + f * 16 + laneK * 4 + r;
        const int sl = f * 4 + r;
        t2k[tloc][wn] = ((u64)v1b[sl] << 32) | c1v[sl];
        t2v[tloc][wn] = v2b[sl];
      }
  }
  __syncthreads();
  if (tid < 64) {
    u64 k0 = t2k[tid][0], k1 = t2k[tid][1];
    u32 va = t2v[tid][0], vb = t2v[tid][1];
    u64 K1 = umin64(k0, k1);
    u32 loser = (u32)(umax64(k0, k1) >> 32);
    u32 V2 = min(min(va, vb), loser);
    const int token = ttile * 128 + thalf * 64 + tid;
    pk1[(size_t)token * 8 + cg] = K1;
    pv2[(size_t)token * 8 + cg] = __uint_as_float(V2);
  }
}

// ---- detect: merge 8 cgroup top-2, write candidate ids, flag near-ties ----
__global__ __launch_bounds__(256)
void vq_detect(const u64* __restrict__ pk1, const float* __restrict__ pv2,
               int* __restrict__ ids, int* __restrict__ rcnt, int* __restrict__ rlist) {
  const int token = blockIdx.x * 256 + threadIdx.x;
  u64 K1 = pk1[(size_t)token * 8];
  float V2 = pv2[(size_t)token * 8];
#pragma unroll
  for (int c = 1; c < 8; ++c) {
    u64 k1 = pk1[(size_t)token * 8 + c];
    float v2 = pv2[(size_t)token * 8 + c];
    u64 n1 = (k1 < K1) ? k1 : K1;
    u64 hi = (k1 < K1) ? K1 : k1;
    float loser = __uint_as_float((unsigned)(hi >> 32));
    V2 = fminf(fminf(V2, v2), loser);
    K1 = n1;
  }
  ids[token] = (int)(K1 & 0xffffffffull);
  float d1 = __uint_as_float((unsigned)(K1 >> 32));
  if (V2 - d1 < RESCUE_TAU) {
    int p = atomicAdd(rcnt, 1);
    rlist[p] = token;
  }
}

// ---- rescue v2: 2-D (32-token batch x 32 code-chunks) exact rescan -------
__global__ __launch_bounds__(256)
void vq_rescue2(const float* __restrict__ z, const float* __restrict__ cb,
                const float* __restrict__ An, const float* __restrict__ Cn,
                const int* __restrict__ rcnt, const int* __restrict__ rlist,
                u64* __restrict__ rmin) {
  const int tid = threadIdx.x;
  const int total = *rcnt;
  if (total == 0) return;
  const int nb = (total + 31) >> 5;   // batches of 32 tokens
  for (int wi = blockIdx.x; wi < nb * 32; wi += gridDim.x) {
    const int batch = wi >> 5, chunk = wi & 31;
    const int base = batch * 32;
    const int np = min(32, total - base);
    int toks[32];
#pragma unroll
    for (int s = 0; s < 32; ++s)
      toks[s] = rlist[base + (s < np ? s : 0)];   // pad with valid token
    const int j = chunk * 256 + tid;
    const float4* crow = reinterpret_cast<const float4*>(cb + (size_t)j * DIM);
    float dots[32];
#pragma unroll
    for (int s = 0; s < 32; ++s) dots[s] = 0.f;
    for (int k4 = 0; k4 < 64; ++k4) {
      const float4 c4 = crow[k4];
#pragma unroll
      for (int s = 0; s < 32; ++s) {   // k ascending, exact R3 chain
        const float4 z4 = *reinterpret_cast<const float4*>(
            z + (size_t)toks[s] * DIM + k4 * 4);
        dots[s] = fmaf(z4.x, c4.x, dots[s]);
        dots[s] = fmaf(z4.y, c4.y, dots[s]);
        dots[s] = fmaf(z4.z, c4.z, dots[s]);
        dots[s] = fmaf(z4.w, c4.w, dots[s]);
      }
    }
    const float Cj = Cn[j];
#pragma unroll
    for (int s = 0; s < 32; ++s) {
      if (s < np) {
        float p2 = __fmul_rn(2.0f, dots[s]);
        float t1 = __fsub_rn(An[toks[s]], p2);
        float t  = __fadd_rn(t1, Cj);
        u64 key = ((u64)__float_as_uint(t) << 32) | (u64)j;
#pragma unroll
        for (int d = 1; d < 64; d <<= 1) {
          u64 o = __shfl_xor(key, d);
          key = o < key ? o : key;
        }
        if ((tid & 63) == 0) atomicMin(&rmin[toks[s]], key);
      }
    }
  }
}

// ---- rescue apply: commit rescued winners into ids ------------------------
__global__ __launch_bounds__(256)
void vq_rescue_apply(const int* __restrict__ rcnt, const int* __restrict__ rlist,
                     const u64* __restrict__ rmin, int* __restrict__ ids) {
  const int total = *rcnt;
  for (int i = blockIdx.x * 256 + threadIdx.x; i < total; i += gridDim.x * 256) {
    const int t = rlist[i];
    ids[t] = (int)(rmin[t] & 0xffffffffull);
  }
}

// ---- finalize: gather z_q, ids; block-reduced loss partials (no atomics) --
__global__ __launch_bounds__(256)
void vq_finalize_ids(const float* __restrict__ z, const float* __restrict__ cb,
                     const int* __restrict__ ids, float* __restrict__ out,
                     double* __restrict__ part) {
  __shared__ double sred[4];
  const int g64 = threadIdx.x >> 6, lane = threadIdx.x & 63;
  double s = 0.0;
#pragma unroll
  for (int i = 0; i < 4; ++i) {
    const int n = blockIdx.x * 16 + i * 4 + g64;
    const int bk = ids[n];
    const float4 c4 = *reinterpret_cast<const float4*>(&cb[(size_t)bk * DIM + lane * 4]);
    const float4 z4 = *reinterpret_cast<const float4*>(&z[(size_t)n * DIM + lane * 4]);
    *reinterpret_cast<float4*>(&out[(size_t)n * DIM + lane * 4]) = c4;
    float dx = __fsub_rn(c4.x, z4.x), dy = __fsub_rn(c4.y, z4.y);
    float dz = __fsub_rn(c4.z, z4.z), dw = __fsub_rn(c4.w, z4.w);
    s += (double)dx * dx + (double)dy * dy + (double)dz * dz + (double)dw * dw;
    if (lane == 0) out[(size_t)NTOK * DIM + n] = (float)bk;
  }
#pragma unroll
  for (int off = 32; off > 0; off >>= 1) s += __shfl_down(s, off);
  if (lane == 0) sred[g64] = s;
  __syncthreads();
  if (threadIdx.x == 0)
    part[blockIdx.x] = (sred[0] + sred[1]) + (sred[2] + sred[3]);
}

__global__ __launch_bounds__(256)
void vq_loss_write(const double* __restrict__ part, float* __restrict__ out) {
  __shared__ double red[256];
  double s = 0.0;
  for (int i = threadIdx.x; i < 2048; i += 256) s += part[i];
  red[threadIdx.x] = s;
  __syncthreads();
  for (int off = 128; off > 0; off >>= 1) {
    if (threadIdx.x < off) red[threadIdx.x] += red[threadIdx.x + off];
    __syncthreads();
  }
  if (threadIdx.x == 0)
    out[(size_t)NTOK * DIM + NTOK] =
        (float)(0.25 * red[0] / (double)((size_t)NTOK * DIM));
}

// ======================= R3 fallback path (ws too small) ==================
#define NCHUNK 8
#define CHUNK 1024
#define TT 128
#define CT 128
#define DC 32

__global__ __launch_bounds__(256)
void vq_argmin_kernel(const float* __restrict__ z, const float* __restrict__ cb,
                      const float* __restrict__ An, const float* __restrict__ Cn,
                      float* __restrict__ pv, int* __restrict__ pk) {
  __shared__ float zs[DC * TT];
  __shared__ float cs[DC * CT];
  const int tid = threadIdx.x;
  const int tx = tid & 15, ty = tid >> 4;
  const int chunk = blockIdx.x & 7;
  const int tile = blockIdx.x >> 3;
  const int base_t = tile * TT;
  const int base_k = chunk * CHUNK;
  float Areg[8];
#pragma unroll
  for (int i = 0; i < 8; ++i) Areg[i] = An[base_t + ty * 8 + i];
  float bestv[8]; int bestk[8];
#pragma unroll
  for (int i = 0; i < 8; ++i) { bestv[i] = INFINITY; bestk[i] = 0; }
  for (int st = 0; st < CHUNK / CT; ++st) {
    const int kb0 = base_k + st * CT;
    float acc[8][8];
#pragma unroll
    for (int i = 0; i < 8; ++i)
#pragma unroll
      for (int j = 0; j < 8; ++j) acc[i][j] = 0.f;
    for (int dc = 0; dc < DIM / DC; ++dc) {
      __syncthreads();
#pragma unroll
      for (int li = tid; li < DC * TT / 4; li += 256) {
        const int row = li >> 3;
        const int dv = li & 7;
        const int ibase = dv * 4 * 128 + (row ^ (dv << 2) ^ ((row & 32) >> 3));
        float4 v = *reinterpret_cast<const float4*>(
            &z[(size_t)(base_t + row) * DIM + dc * DC + dv * 4]);
        zs[ibase] = v.x; zs[ibase + 128] = v.y;
        zs[ibase + 256] = v.z; zs[ibase + 384] = v.w;
        float4 c = *reinterpret_cast<const float4*>(
            &cb[(size_t)(kb0 + row) * DIM + dc * DC + dv * 4]);
        cs[ibase] = c.x; cs[ibase + 128] = c.y;
        cs[ibase + 256] = c.z; cs[ibase + 384] = c.w;
      }
      __syncthreads();
#pragma unroll
      for (int dd = 0; dd < DC / 4; ++dd) {
        const int s1 = dd << 2;
        const float* zp0 = &zs[dd * 4 * 128 + ((ty * 8) ^ s1 ^ (ty & 4))];
        const float* zp1 = &zs[dd * 4 * 128 + ((ty * 8 + 4) ^ s1 ^ (ty & 4))];
        const float* cp0 = &cs[dd * 4 * 128 + ((tx * 8) ^ s1 ^ (tx & 4))];
        const float* cp1 = &cs[dd * 4 * 128 + ((tx * 8 + 4) ^ s1 ^ (tx & 4))];
#pragma unroll
        for (int q = 0; q < 4; ++q) {
          const float4 za  = *reinterpret_cast<const float4*>(zp0 + q * 128);
          const float4 zb  = *reinterpret_cast<const float4*>(zp1 + q * 128);
          const float4 ca  = *reinterpret_cast<const float4*>(cp0 + q * 128);
          const float4 cbv = *reinterpret_cast<const float4*>(cp1 + q * 128);
          const float zv[8] = {za.x, za.y, za.z, za.w, zb.x, zb.y, zb.z, zb.w};
          const float cv[8] = {ca.x, ca.y, ca.z, ca.w, cbv.x, cbv.y, cbv.z, cbv.w};
#pragma unroll
          for (int i = 0; i < 8; ++i)
#pragma unroll
            for (int j = 0; j < 8; ++j)
              acc[i][j] = fmaf(zv[i], cv[j], acc[i][j]);
        }
      }
    }
#pragma unroll
    for (int j = 0; j < 8; ++j) {
      const int klocal = st * CT + tx * 8 + j;
      const float Ck = Cn[base_k + klocal];
#pragma unroll
      for (int i = 0; i < 8; ++i) {
        float p2 = __fmul_rn(2.0f, acc[i][j]);
        float t1 = __fsub_rn(Areg[i], p2);
        float t  = __fadd_rn(t1, Ck);
        if (t < bestv[i]) { bestv[i] = t; bestk[i] = klocal; }
      }
    }
  }
  __syncthreads();
  float (*mv)[16] = reinterpret_cast<float(*)[16]>(zs);
  int   (*mk)[16] = reinterpret_cast<int(*)[16]>(zs + TT * 16);
#pragma unroll
  for (int i = 0; i < 8; ++i) { mv[ty * 8 + i][tx] = bestv[i]; mk[ty * 8 + i][tx] = bestk[i]; }
  __syncthreads();
  if (tid < TT) {
    float bv = mv[tid][0]; int bk = mk[tid][0];
#pragma unroll
    for (int x = 1; x < 16; ++x) {
      float v = mv[tid][x]; int k = mk[tid][x];
      if (v < bv || (v == bv && k < bk)) { bv = v; bk = k; }
    }
    size_t idx = (size_t)(base_t + tid) * NCHUNK + chunk;
    pv[idx] = bv;
    pk[idx] = base_k + bk;
  }
}

__global__ __launch_bounds__(256)
void vq_finalize(const float* __restrict__ z, const float* __restrict__ cb,
                 const float* __restrict__ pv, const int* __restrict__ pk,
                 float* __restrict__ out, double* __restrict__ loss_acc) {
  const int n = blockIdx.x * 4 + (threadIdx.x >> 6);
  const int lane = threadIdx.x & 63;
  float bv = INFINITY; int bk = 0;
#pragma unroll
  for (int c = 0; c < NCHUNK; ++c) {
    float v = pv[(size_t)n * NCHUNK + c];
    int k = pk[(size_t)n * NCHUNK + c];
    if (v < bv || (v == bv && k < bk)) { bv = v; bk = k; }
  }
  const float4 c4 = *reinterpret_cast<const float4*>(&cb[(size_t)bk * DIM + lane * 4]);
  const float4 z4 = *reinterpret_cast<const float4*>(&z[(size_t)n * DIM + lane * 4]);
  *reinterpret_cast<float4*>(&out[(size_t)n * DIM + lane * 4]) = c4;
  float dx = __fsub_rn(c4.x, z4.x), dy = __fsub_rn(c4.y, z4.y);
  float dz = __fsub_rn(c4.z, z4.z), dw = __fsub_rn(c4.w, z4.w);
  double s = (double)dx * dx + (double)dy * dy + (double)dz * dz + (double)dw * dw;
#pragma unroll
  for (int off = 32; off > 0; off >>= 1) s += __shfl_down(s, off);
  if (lane == 0) {
    out[(size_t)NTOK * DIM + n] = (float)bk;
    atomicAdd(loss_acc, s);
  }
}

__global__ void vq_loss_write_fb(const double* __restrict__ loss_acc, float* __restrict__ out) {
  out[(size_t)NTOK * DIM + NTOK] = (float)(0.25 * (*loss_acc) / (double)((size_t)NTOK * DIM));
}

// ==========================================================================
extern "C" void kernel_launch(void* const* d_in, const int* in_sizes, int n_in,
                              void* d_out, int out_size, void* d_ws, size_t ws_size,
                              hipStream_t stream) {
  const float* z  = (const float*)d_in[0];
  const float* cb = (const float*)d_in[1];
  float* out = (float*)d_out;
  char* ws = (char*)d_ws;

  if (ws_size >= WS_NEED) {
    float*     An   = (float*)(ws + OFF_AN);
    float*     Cn   = (float*)(ws + OFF_CN);
    int*       ids  = (int*)(ws + OFF_IDS);
    int*       rcnt = (int*)(ws + OFF_RCNT);
    int*       rlist= (int*)(ws + OFF_RLIST);
    double*    part = (double*)(ws + OFF_PART);
    u64*       pk1  = (u64*)(ws + OFF_PK1);
    float*     pv2  = (float*)(ws + OFF_PV2);
    _Float16*  z16  = (_Float16*)(ws + OFF_Z16);
    _Float16*  c16h = (_Float16*)(ws + OFF_CB16);
    u64*       rmin = pk1;   // first 256 KB of pk1 reused after detect

    hipMemsetAsync(rcnt, 0, 128, stream);
    rownorm256_np<<<NTOK / 256, 256, 0, stream>>>(z, An, NTOK);
    rownorm256_np<<<KCB / 256, 256, 0, stream>>>(cb, Cn, KCB);
    conv_z16<<<256 * 8, 128, 0, stream>>>(z, z16);
    conv_cb16h<<<32 * 8, 256, 0, stream>>>(cb, c16h);
    vq_mfma_top2<<<4096, 256, 0, stream>>>(z16, c16h, An, Cn, pk1, pv2);
    vq_detect<<<NTOK / 256, 256, 0, stream>>>(pk1, pv2, ids, rcnt, rlist);
    hipMemsetAsync(rmin, 0xFF, (size_t)NTOK * sizeof(u64), stream);  // after detect
    vq_rescue2<<<2048, 256, 0, stream>>>(z, cb, An, Cn, rcnt, rlist, rmin);
    vq_rescue_apply<<<32, 256, 0, stream>>>(rcnt, rlist, rmin, ids);
    vq_finalize_ids<<<NTOK / 16, 256, 0, stream>>>(z, cb, ids, out, part);
    vq_loss_write<<<1, 256, 0, stream>>>(part, out);
  } else {
    // R3 fallback (needs ~2.26 MB)
    float*  An = (float*)(ws);
    float*  Cn = (float*)(ws + 131072);
    float*  pv = (float*)(ws + 163840);
    int*    pk = (int*)(ws + 1212416);
    double* loss = (double*)(ws + 2260992);
    hipMemsetAsync(loss, 0, sizeof(double), stream);
    rownorm256_np<<<NTOK / 256, 256, 0, stream>>>(z, An, NTOK);
    rownorm256_np<<<KCB / 256, 256, 0, stream>>>(cb, Cn, KCB);
    vq_argmin_kernel<<<(NTOK / TT) * NCHUNK, 256, 0, stream>>>(z, cb, An, Cn, pv, pk);
    vq_finalize<<<NTOK / 4, 256, 0, stream>>>(z, cb, pv, pk, out, loss);
    vq_loss_write_fb<<<1, 1, 0, stream>>>(loss, out);
  }
}

// Round 20
// 593.583 us; speedup vs baseline: 1.2085x; 1.2085x over previous
//
#include <hip/hip_runtime.h>
#include <math.h>

#define NTOK 32768
#define DIM 256
#define KCB 8192
#define RESCUE_TAU 4e-3f

typedef _Float16 half8 __attribute__((ext_vector_type(8)));
typedef float f32x4 __attribute__((ext_vector_type(4)));
typedef unsigned long long u64;
typedef unsigned int u32;

// ---------------- fast-path ws layout (bytes) ----------------
#define OFF_AN    0ull
#define OFF_CN    131072ull
#define OFF_IDS   163840ull
#define OFF_RCNT  294912ull
#define OFF_RLIST 295040ull
#define OFF_PART  426112ull      // 2048 doubles
#define OFF_PK1   442496ull      // u64 [32768][8]; first 256KB reused as rmin[]
#define OFF_PV2   2539648ull     // f32 [32768][8]
#define OFF_Z16   3588224ull     // [256 tile][8 ks][128 row][64 halves swz]
#define OFF_CB16  37142656ull    // cb16h: [32 tile][8 ks][256 row][32 halves swz]
#define WS_NEED   45531264ull

#define GLOAD_LDS16(gp, lp) __builtin_amdgcn_global_load_lds( \
    (const __attribute__((address_space(1))) void*)(gp), \
    (__attribute__((address_space(3))) void*)(lp), 16, 0, 0)

static __device__ __forceinline__ u64 umin64(u64 a, u64 b) { return a < b ? a : b; }
static __device__ __forceinline__ u64 umax64(u64 a, u64 b) { return a < b ? b : a; }

// ---- numpy-pairwise ||row||^2 (bitwise-matching np.sum(x*x,axis=1)) ------
__global__ __launch_bounds__(256)
void rownorm256_np(const float* __restrict__ M, float* __restrict__ out, int rows) {
  int r = blockIdx.x * 256 + threadIdx.x;
  if (r >= rows) return;
  const float* p = M + (size_t)r * DIM;
  float blk[2];
#pragma unroll
  for (int b = 0; b < 2; ++b) {
    const float* a = p + b * 128;
    float rr[8];
#pragma unroll
    for (int j = 0; j < 8; ++j) rr[j] = __fmul_rn(a[j], a[j]);
    for (int i = 8; i < 128; i += 8) {
#pragma unroll
      for (int j = 0; j < 8; ++j)
        rr[j] = __fadd_rn(rr[j], __fmul_rn(a[i + j], a[i + j]));
    }
    float s01 = __fadd_rn(rr[0], rr[1]);
    float s23 = __fadd_rn(rr[2], rr[3]);
    float s45 = __fadd_rn(rr[4], rr[5]);
    float s67 = __fadd_rn(rr[6], rr[7]);
    blk[b] = __fadd_rn(__fadd_rn(s01, s23), __fadd_rn(s45, s67));
  }
  out[r] = __fadd_rn(blk[0], blk[1]);
}

// ---- convert z: fp32 -> scaled fp16 (hi,lo) pair, pre-swizzled (UNCHANGED) --
__global__ __launch_bounds__(128)
void conv_z16(const float* __restrict__ z, _Float16* __restrict__ dst) {
  const int tile = blockIdx.x >> 3, ks = blockIdx.x & 7, row = threadIdx.x;
  const float* src = z + ((size_t)(tile * 128 + row)) * DIM + ks * 32;
  _Float16* d = dst + (u64)tile * 65536 + (u64)ks * 8192 + row * 64;
  const int rs = row & 7;
#pragma unroll
  for (int q = 0; q < 4; ++q) {
    half8 hv, lv;
#pragma unroll
    for (int j = 0; j < 8; ++j) {
      float f = src[q * 8 + j] * 64.0f;          // exact pow2 scale
      _Float16 h = (_Float16)f;                  // RNE
      float lf = f - (float)h;                   // exact
      hv[j] = h; lv[j] = (_Float16)lf;
    }
    *reinterpret_cast<half8*>(d + ((q ^ rs) * 8)) = hv;
    *reinterpret_cast<half8*>(d + (((q + 4) ^ rs) * 8)) = lv;
  }
}

// ---- convert cb: HI PLANE ONLY, compact rows of 32 halves ----------------
// layout: cb16h[tile*65536 + ks*8192 + row*32 + (q ^ ((row>>1)&3))*8 + j]
// swizzle (row>>1)&3: bank(first word) = (16*row + 4*(q^sw)) mod 32 covers
// 8 distinct banks over 8 consecutive rows -> 2 lanes/bank on read (free).
// (R19's row&3 gave only 4 banks -> 4-way conflict, 1.7e7 counted.)
__global__ __launch_bounds__(256)
void conv_cb16h(const float* __restrict__ cb, _Float16* __restrict__ dst) {
  const int tile = blockIdx.x >> 3, ks = blockIdx.x & 7, row = threadIdx.x;
  const float* src = cb + ((size_t)(tile * 256 + row)) * DIM + ks * 32;
  _Float16* d = dst + (u64)tile * 65536 + (u64)ks * 8192 + row * 32;
  const int rs = (row >> 1) & 3;
#pragma unroll
  for (int q = 0; q < 4; ++q) {
    half8 hv;
#pragma unroll
    for (int j = 0; j < 8; ++j) {
      float f = src[q * 8 + j] * 1024.0f;        // exact pow2 scale
      hv[j] = (_Float16)f;                       // RNE hi
    }
    *reinterpret_cast<half8*>(d + ((q ^ rs) * 8)) = hv;
  }
}

// ---- MFMA GEMM + per-LANE top-2: A(hi+lo) in regs, B hi-only via LDS -----
// Block: 64 tokens x 128 codes, 4 waves (2m x 2n), wave-tile 32x64.
// Split: dot ~= (zh+zl)*ch; dropped z''*cl 6-sigma ~8.4e-4 << TAU/2.
// launch_bounds(256,2): R19's (256,3) made the allocator chase 6 waves/SIMD
// (VGPR clamp 84) and SPILL Ah[8][4] (WRITE_SIZE 282MB). R13 proved (256,2)
// holds Ah[8][4] at VGPR=128 spill-free.
__global__ __launch_bounds__(256, 2)
void vq_mfma_top2(const _Float16* __restrict__ z16, const _Float16* __restrict__ cb16h,
                  const float* __restrict__ An, const float* __restrict__ Cn,
                  u64* __restrict__ pk1, float* __restrict__ pv2) {
  __shared__ _Float16 Bs0[128 * 32];   // 8 KB
  __shared__ _Float16 Bs1[128 * 32];   // 8 KB
  __shared__ float    Cs[1024];        // 4 KB  (this cg's code norms)
  __shared__ u64      t2k[64][2];      // 1 KB
  __shared__ u32      t2v[64][2];      // 0.5 KB

  const int tid = threadIdx.x;
  const int lane = tid & 63, w = tid >> 6;
  const int wm = w >> 1, wn = w & 1;
  // XCD swizzle: grid 4096, 8 XCDs -> each XCD owns exactly one cgroup
  const int swz = (blockIdx.x & 7) * 512 + (blockIdx.x >> 3);
  const int cg = swz >> 9, rem = swz & 511;
  const int ttile = rem >> 1, thalf = rem & 1;
  const int laneM = lane & 15, laneK = lane >> 4;
  const _Float16* zt = z16 + (u64)ttile * 65536;

  // A-fragment per-lane offsets: hi plane [0..1], lo plane [2..3] (R13 formula)
  int offA[4];
#pragma unroll
  for (int f = 0; f < 2; ++f) {
    int row = thalf * 64 + wm * 32 + f * 16 + laneM;
    offA[f]     = row * 64 + ((laneK ^ (row & 7)) * 8);
    offA[f + 2] = row * 64 + (((laneK + 4) ^ (row & 7)) * 8);
  }
  // B-fragment offsets in compact 32-half rows (granule = laneK^((row>>1)&3))
  int offBh[4];
#pragma unroll
  for (int g = 0; g < 4; ++g) {
    int row = wn * 64 + g * 16 + laneM;
    offBh[g] = row * 32 + ((laneK ^ ((row >> 1) & 3)) * 8);
  }

  // preload A hi+lo fragments (8 ks x 4 half8) -> registers, once
  half8 Ah[8][4];
#pragma unroll
  for (int ks = 0; ks < 8; ++ks)
#pragma unroll
    for (int f = 0; f < 4; ++f)
      Ah[ks][f] = *reinterpret_cast<const half8*>(zt + ks * 8192 + offA[f]);

  // token norms
  float Areg[2][4];
#pragma unroll
  for (int f = 0; f < 2; ++f) {
    float4 a4 = *reinterpret_cast<const float4*>(
        &An[ttile * 128 + thalf * 64 + wm * 32 + f * 16 + laneK * 4]);
    Areg[f][0] = a4.x; Areg[f][1] = a4.y; Areg[f][2] = a4.z; Areg[f][3] = a4.w;
  }
  {  // stage this cg's code norms into LDS
    float4 c4 = *reinterpret_cast<const float4*>(&Cn[cg * 1024 + tid * 4]);
    *reinterpret_cast<float4*>(&Cs[tid * 4]) = c4;
  }

  // per-lane top-2 state: 8 token-slots
  u32 v1b[8], v2b[8], c1v[8];
#pragma unroll
  for (int s = 0; s < 8; ++s) { v1b[s] = 0x7F800000u; v2b[s] = 0x7F800000u; c1v[s] = 0; }
  u32 codeSub = (u32)(cg * 1024 + wn * 64 + laneM);  // += 128 per sub

// stage one 128-code hi-plane tile (8KB) as TWO lane-linear 4KB chunks
// (16B per lane per instruction => dest stride == width, valid for gload_lds)
#define STAGE_B(s, Bd) do {                                                  \
    const int ns_ = (s) >> 3, nk_ = (s) & 7;                                 \
    const _Float16* sb_ = cb16h + (u64)(cg * 4 + (ns_ >> 1)) * 65536 +       \
                          (u64)nk_ * 8192 + (u64)(ns_ & 1) * 4096 + tid * 8; \
    GLOAD_LDS16(sb_,        &Bd[tid * 8]);                                   \
    GLOAD_LDS16(sb_ + 2048, &Bd[tid * 8 + 2048]);                            \
  } while (0)

// 2-pass on A: AhHi x bh + AhLo x bh  (16 MFMA per step, B read once)
#define COMPUTE_KS(kc, Bsrc) do {                                            \
    _Pragma("unroll")                                                        \
    for (int g_ = 0; g_ < 4; ++g_) {                                         \
      half8 bh = *reinterpret_cast<const half8*>(&Bsrc[offBh[g_]]);          \
      _Pragma("unroll")                                                      \
      for (int f_ = 0; f_ < 2; ++f_)                                         \
        acc[f_][g_] = __builtin_amdgcn_mfma_f32_16x16x32_f16(Ah[kc][f_], bh, acc[f_][g_], 0, 0, 0);     \
      _Pragma("unroll")                                                      \
      for (int f_ = 0; f_ < 2; ++f_)                                         \
        acc[f_][g_] = __builtin_amdgcn_mfma_f32_16x16x32_f16(Ah[kc][f_ + 2], bh, acc[f_][g_], 0, 0, 0); \
    }                                                                        \
  } while (0)

  // prologue: stage step 0 into Bs0
  STAGE_B(0, Bs0);
  __syncthreads();   // Bs0 + Cs ready

  f32x4 acc[2][4];
#pragma unroll
  for (int f = 0; f < 2; ++f)
#pragma unroll
    for (int g = 0; g < 4; ++g) acc[f][g] = (f32x4){0.f, 0.f, 0.f, 0.f};

  for (int sub = 0; sub < 8; ++sub) {
#pragma unroll
    for (int ks = 0; ks < 8; ++ks) {
      const int step = sub * 8 + ks;
      if (step < 63) {
        if (ks & 1) STAGE_B(step + 1, Bs0);
        else        STAGE_B(step + 1, Bs1);
      }
      if (ks & 1) COMPUTE_KS(ks, Bs1);
      else        COMPUTE_KS(ks, Bs0);

      if (ks == 7) {  // sub complete: per-lane top-2 update
        const int cbase = sub * 128 + wn * 64 + laneM;
        float Cg[4];
#pragma unroll
        for (int g = 0; g < 4; ++g) Cg[g] = Cs[cbase + g * 16];
#pragma unroll
        for (int f = 0; f < 2; ++f) {
#pragma unroll
          for (int r = 0; r < 4; ++r) {
            const int sl = f * 4 + r;
            const float Ar = Areg[f][r];
#pragma unroll
            for (int g = 0; g < 4; ++g) {
              float p2 = __fmul_rn(acc[f][g][r], 0x1p-15f);   // 2*dot, exact pow2
              float t1 = __fsub_rn(Ar, p2);
              float t  = __fadd_rn(t1, Cg[g]);
              u32 tb = __float_as_uint(t);        // t>0 -> bit cmp == float cmp
              u32 code = codeSub + (u32)(g * 16);
              bool lt1 = tb < v1b[sl];
              bool lt2 = tb < v2b[sl];
              v2b[sl] = lt1 ? v1b[sl] : (lt2 ? tb : v2b[sl]);
              c1v[sl] = lt1 ? code : c1v[sl];
              v1b[sl] = lt1 ? tb : v1b[sl];
            }
          }
        }
        codeSub += 128;
#pragma unroll
        for (int f = 0; f < 2; ++f)
#pragma unroll
          for (int g = 0; g < 4; ++g) acc[f][g] = (f32x4){0.f, 0.f, 0.f, 0.f};
      }
      __syncthreads();   // staged buffer ready; all waves done reading cur
    }
  }

#undef STAGE_B
#undef COMPUTE_KS

  // final cross-lane (laneM) top-2 reduce, once per kernel
#pragma unroll
  for (int sl = 0; sl < 8; ++sl) {
#pragma unroll
    for (int d = 1; d < 16; d <<= 1) {
      u32 o1 = (u32)__shfl_xor((int)v1b[sl], d);
      u32 oc = (u32)__shfl_xor((int)c1v[sl], d);
      u32 o2 = (u32)__shfl_xor((int)v2b[sl], d);
      u64 k  = ((u64)v1b[sl] << 32) | c1v[sl];
      u64 ko = ((u64)o1 << 32) | oc;
      u32 loser = v1b[sl] < o1 ? o1 : v1b[sl];
      u32 nv2 = min(loser, min(v2b[sl], o2));
      u64 nk = umin64(k, ko);
      v1b[sl] = (u32)(nk >> 32); c1v[sl] = (u32)nk; v2b[sl] = nv2;
    }
  }
  if (laneM == 0) {
#pragma unroll
    for (int f = 0; f < 2; ++f)
#pragma unroll
      for (int r = 0; r < 4; ++r) {
        const int tloc = wm * 32 + f * 16 + laneK * 4 + r;
        const int sl = f * 4 + r;
        t2k[tloc][wn] = ((u64)v1b[sl] << 32) | c1v[sl];
        t2v[tloc][wn] = v2b[sl];
      }
  }
  __syncthreads();
  if (tid < 64) {
    u64 k0 = t2k[tid][0], k1 = t2k[tid][1];
    u32 va = t2v[tid][0], vb = t2v[tid][1];
    u64 K1 = umin64(k0, k1);
    u32 loser = (u32)(umax64(k0, k1) >> 32);
    u32 V2 = min(min(va, vb), loser);
    const int token = ttile * 128 + thalf * 64 + tid;
    pk1[(size_t)token * 8 + cg] = K1;
    pv2[(size_t)token * 8 + cg] = __uint_as_float(V2);
  }
}

// ---- detect: merge 8 cgroup top-2, write candidate ids, flag near-ties ----
__global__ __launch_bounds__(256)
void vq_detect(const u64* __restrict__ pk1, const float* __restrict__ pv2,
               int* __restrict__ ids, int* __restrict__ rcnt, int* __restrict__ rlist) {
  const int token = blockIdx.x * 256 + threadIdx.x;
  u64 K1 = pk1[(size_t)token * 8];
  float V2 = pv2[(size_t)token * 8];
#pragma unroll
  for (int c = 1; c < 8; ++c) {
    u64 k1 = pk1[(size_t)token * 8 + c];
    float v2 = pv2[(size_t)token * 8 + c];
    u64 n1 = (k1 < K1) ? k1 : K1;
    u64 hi = (k1 < K1) ? K1 : k1;
    float loser = __uint_as_float((unsigned)(hi >> 32));
    V2 = fminf(fminf(V2, v2), loser);
    K1 = n1;
  }
  ids[token] = (int)(K1 & 0xffffffffull);
  float d1 = __uint_as_float((unsigned)(K1 >> 32));
  if (V2 - d1 < RESCUE_TAU) {
    int p = atomicAdd(rcnt, 1);
    rlist[p] = token;
  }
}

// ---- rescue v2: 2-D (32-token batch x 32 code-chunks) exact rescan -------
__global__ __launch_bounds__(256)
void vq_rescue2(const float* __restrict__ z, const float* __restrict__ cb,
                const float* __restrict__ An, const float* __restrict__ Cn,
                const int* __restrict__ rcnt, const int* __restrict__ rlist,
                u64* __restrict__ rmin) {
  const int tid = threadIdx.x;
  const int total = *rcnt;
  if (total == 0) return;
  const int nb = (total + 31) >> 5;   // batches of 32 tokens
  for (int wi = blockIdx.x; wi < nb * 32; wi += gridDim.x) {
    const int batch = wi >> 5, chunk = wi & 31;
    const int base = batch * 32;
    const int np = min(32, total - base);
    int toks[32];
#pragma unroll
    for (int s = 0; s < 32; ++s)
      toks[s] = rlist[base + (s < np ? s : 0)];   // pad with valid token
    const int j = chunk * 256 + tid;
    const float4* crow = reinterpret_cast<const float4*>(cb + (size_t)j * DIM);
    float dots[32];
#pragma unroll
    for (int s = 0; s < 32; ++s) dots[s] = 0.f;
    for (int k4 = 0; k4 < 64; ++k4) {
      const float4 c4 = crow[k4];
#pragma unroll
      for (int s = 0; s < 32; ++s) {   // k ascending, exact R3 chain
        const float4 z4 = *reinterpret_cast<const float4*>(
            z + (size_t)toks[s] * DIM + k4 * 4);
        dots[s] = fmaf(z4.x, c4.x, dots[s]);
        dots[s] = fmaf(z4.y, c4.y, dots[s]);
        dots[s] = fmaf(z4.z, c4.z, dots[s]);
        dots[s] = fmaf(z4.w, c4.w, dots[s]);
      }
    }
    const float Cj = Cn[j];
#pragma unroll
    for (int s = 0; s < 32; ++s) {
      if (s < np) {
        float p2 = __fmul_rn(2.0f, dots[s]);
        float t1 = __fsub_rn(An[toks[s]], p2);
        float t  = __fadd_rn(t1, Cj);
        u64 key = ((u64)__float_as_uint(t) << 32) | (u64)j;
#pragma unroll
        for (int d = 1; d < 64; d <<= 1) {
          u64 o = __shfl_xor(key, d);
          key = o < key ? o : key;
        }
        if ((tid & 63) == 0) atomicMin(&rmin[toks[s]], key);
      }
    }
  }
}

// ---- rescue apply: commit rescued winners into ids ------------------------
__global__ __launch_bounds__(256)
void vq_rescue_apply(const int* __restrict__ rcnt, const int* __restrict__ rlist,
                     const u64* __restrict__ rmin, int* __restrict__ ids) {
  const int total = *rcnt;
  for (int i = blockIdx.x * 256 + threadIdx.x; i < total; i += gridDim.x * 256) {
    const int t = rlist[i];
    ids[t] = (int)(rmin[t] & 0xffffffffull);
  }
}

// ---- finalize: gather z_q, ids; block-reduced loss partials (no atomics) --
__global__ __launch_bounds__(256)
void vq_finalize_ids(const float* __restrict__ z, const float* __restrict__ cb,
                     const int* __restrict__ ids, float* __restrict__ out,
                     double* __restrict__ part) {
  __shared__ double sred[4];
  const int g64 = threadIdx.x >> 6, lane = threadIdx.x & 63;
  double s = 0.0;
#pragma unroll
  for (int i = 0; i < 4; ++i) {
    const int n = blockIdx.x * 16 + i * 4 + g64;
    const int bk = ids[n];
    const float4 c4 = *reinterpret_cast<const float4*>(&cb[(size_t)bk * DIM + lane * 4]);
    const float4 z4 = *reinterpret_cast<const float4*>(&z[(size_t)n * DIM + lane * 4]);
    *reinterpret_cast<float4*>(&out[(size_t)n * DIM + lane * 4]) = c4;
    float dx = __fsub_rn(c4.x, z4.x), dy = __fsub_rn(c4.y, z4.y);
    float dz = __fsub_rn(c4.z, z4.z), dw = __fsub_rn(c4.w, z4.w);
    s += (double)dx * dx + (double)dy * dy + (double)dz * dz + (double)dw * dw;
    if (lane == 0) out[(size_t)NTOK * DIM + n] = (float)bk;
  }
#pragma unroll
  for (int off = 32; off > 0; off >>= 1) s += __shfl_down(s, off);
  if (lane == 0) sred[g64] = s;
  __syncthreads();
  if (threadIdx.x == 0)
    part[blockIdx.x] = (sred[0] + sred[1]) + (sred[2] + sred[3]);
}

__global__ __launch_bounds__(256)
void vq_loss_write(const double* __restrict__ part, float* __restrict__ out) {
  __shared__ double red[256];
  double s = 0.0;
  for (int i = threadIdx.x; i < 2048; i += 256) s += part[i];
  red[threadIdx.x] = s;
  __syncthreads();
  for (int off = 128; off > 0; off >>= 1) {
    if (threadIdx.x < off) red[threadIdx.x] += red[threadIdx.x + off];
    __syncthreads();
  }
  if (threadIdx.x == 0)
    out[(size_t)NTOK * DIM + NTOK] =
        (float)(0.25 * red[0] / (double)((size_t)NTOK * DIM));
}

// ======================= R3 fallback path (ws too small) ==================
#define NCHUNK 8
#define CHUNK 1024
#define TT 128
#define CT 128
#define DC 32

__global__ __launch_bounds__(256)
void vq_argmin_kernel(const float* __restrict__ z, const float* __restrict__ cb,
                      const float* __restrict__ An, const float* __restrict__ Cn,
                      float* __restrict__ pv, int* __restrict__ pk) {
  __shared__ float zs[DC * TT];
  __shared__ float cs[DC * CT];
  const int tid = threadIdx.x;
  const int tx = tid & 15, ty = tid >> 4;
  const int chunk = blockIdx.x & 7;
  const int tile = blockIdx.x >> 3;
  const int base_t = tile * TT;
  const int base_k = chunk * CHUNK;
  float Areg[8];
#pragma unroll
  for (int i = 0; i < 8; ++i) Areg[i] = An[base_t + ty * 8 + i];
  float bestv[8]; int bestk[8];
#pragma unroll
  for (int i = 0; i < 8; ++i) { bestv[i] = INFINITY; bestk[i] = 0; }
  for (int st = 0; st < CHUNK / CT; ++st) {
    const int kb0 = base_k + st * CT;
    float acc[8][8];
#pragma unroll
    for (int i = 0; i < 8; ++i)
#pragma unroll
      for (int j = 0; j < 8; ++j) acc[i][j] = 0.f;
    for (int dc = 0; dc < DIM / DC; ++dc) {
      __syncthreads();
#pragma unroll
      for (int li = tid; li < DC * TT / 4; li += 256) {
        const int row = li >> 3;
        const int dv = li & 7;
        const int ibase = dv * 4 * 128 + (row ^ (dv << 2) ^ ((row & 32) >> 3));
        float4 v = *reinterpret_cast<const float4*>(
            &z[(size_t)(base_t + row) * DIM + dc * DC + dv * 4]);
        zs[ibase] = v.x; zs[ibase + 128] = v.y;
        zs[ibase + 256] = v.z; zs[ibase + 384] = v.w;
        float4 c = *reinterpret_cast<const float4*>(
            &cb[(size_t)(kb0 + row) * DIM + dc * DC + dv * 4]);
        cs[ibase] = c.x; cs[ibase + 128] = c.y;
        cs[ibase + 256] = c.z; cs[ibase + 384] = c.w;
      }
      __syncthreads();
#pragma unroll
      for (int dd = 0; dd < DC / 4; ++dd) {
        const int s1 = dd << 2;
        const float* zp0 = &zs[dd * 4 * 128 + ((ty * 8) ^ s1 ^ (ty & 4))];
        const float* zp1 = &zs[dd * 4 * 128 + ((ty * 8 + 4) ^ s1 ^ (ty & 4))];
        const float* cp0 = &cs[dd * 4 * 128 + ((tx * 8) ^ s1 ^ (tx & 4))];
        const float* cp1 = &cs[dd * 4 * 128 + ((tx * 8 + 4) ^ s1 ^ (tx & 4))];
#pragma unroll
        for (int q = 0; q < 4; ++q) {
          const float4 za  = *reinterpret_cast<const float4*>(zp0 + q * 128);
          const float4 zb  = *reinterpret_cast<const float4*>(zp1 + q * 128);
          const float4 ca  = *reinterpret_cast<const float4*>(cp0 + q * 128);
          const float4 cbv = *reinterpret_cast<const float4*>(cp1 + q * 128);
          const float zv[8] = {za.x, za.y, za.z, za.w, zb.x, zb.y, zb.z, zb.w};
          const float cv[8] = {ca.x, ca.y, ca.z, ca.w, cbv.x, cbv.y, cbv.z, cbv.w};
#pragma unroll
          for (int i = 0; i < 8; ++i)
#pragma unroll
            for (int j = 0; j < 8; ++j)
              acc[i][j] = fmaf(zv[i], cv[j], acc[i][j]);
        }
      }
    }
#pragma unroll
    for (int j = 0; j < 8; ++j) {
      const int klocal = st * CT + tx * 8 + j;
      const float Ck = Cn[base_k + klocal];
#pragma unroll
      for (int i = 0; i < 8; ++i) {
        float p2 = __fmul_rn(2.0f, acc[i][j]);
        float t1 = __fsub_rn(Areg[i], p2);
        float t  = __fadd_rn(t1, Ck);
        if (t < bestv[i]) { bestv[i] = t; bestk[i] = klocal; }
      }
    }
  }
  __syncthreads();
  float (*mv)[16] = reinterpret_cast<float(*)[16]>(zs);
  int   (*mk)[16] = reinterpret_cast<int(*)[16]>(zs + TT * 16);
#pragma unroll
  for (int i = 0; i < 8; ++i) { mv[ty * 8 + i][tx] = bestv[i]; mk[ty * 8 + i][tx] = bestk[i]; }
  __syncthreads();
  if (tid < TT) {
    float bv = mv[tid][0]; int bk = mk[tid][0];
#pragma unroll
    for (int x = 1; x < 16; ++x) {
      float v = mv[tid][x]; int k = mk[tid][x];
      if (v < bv || (v == bv && k < bk)) { bv = v; bk = k; }
    }
    size_t idx = (size_t)(base_t + tid) * NCHUNK + chunk;
    pv[idx] = bv;
    pk[idx] = base_k + bk;
  }
}

__global__ __launch_bounds__(256)
void vq_finalize(const float* __restrict__ z, const float* __restrict__ cb,
                 const float* __restrict__ pv, const int* __restrict__ pk,
                 float* __restrict__ out, double* __restrict__ loss_acc) {
  const int n = blockIdx.x * 4 + (threadIdx.x >> 6);
  const int lane = threadIdx.x & 63;
  float bv = INFINITY; int bk = 0;
#pragma unroll
  for (int c = 0; c < NCHUNK; ++c) {
    float v = pv[(size_t)n * NCHUNK + c];
    int k = pk[(size_t)n * NCHUNK + c];
    if (v < bv || (v == bv && k < bk)) { bv = v; bk = k; }
  }
  const float4 c4 = *reinterpret_cast<const float4*>(&cb[(size_t)bk * DIM + lane * 4]);
  const float4 z4 = *reinterpret_cast<const float4*>(&z[(size_t)n * DIM + lane * 4]);
  *reinterpret_cast<float4*>(&out[(size_t)n * DIM + lane * 4]) = c4;
  float dx = __fsub_rn(c4.x, z4.x), dy = __fsub_rn(c4.y, z4.y);
  float dz = __fsub_rn(c4.z, z4.z), dw = __fsub_rn(c4.w, z4.w);
  double s = (double)dx * dx + (double)dy * dy + (double)dz * dz + (double)dw * dw;
#pragma unroll
  for (int off = 32; off > 0; off >>= 1) s += __shfl_down(s, off);
  if (lane == 0) {
    out[(size_t)NTOK * DIM + n] = (float)bk;
    atomicAdd(loss_acc, s);
  }
}

__global__ void vq_loss_write_fb(const double* __restrict__ loss_acc, float* __restrict__ out) {
  out[(size_t)NTOK * DIM + NTOK] = (float)(0.25 * (*loss_acc) / (double)((size_t)NTOK * DIM));
}

// ==========================================================================
extern "C" void kernel_launch(void* const* d_in, const int* in_sizes, int n_in,
                              void* d_out, int out_size, void* d_ws, size_t ws_size,
                              hipStream_t stream) {
  const float* z  = (const float*)d_in[0];
  const float* cb = (const float*)d_in[1];
  float* out = (float*)d_out;
  char* ws = (char*)d_ws;

  if (ws_size >= WS_NEED) {
    float*     An   = (float*)(ws + OFF_AN);
    float*     Cn   = (float*)(ws + OFF_CN);
    int*       ids  = (int*)(ws + OFF_IDS);
    int*       rcnt = (int*)(ws + OFF_RCNT);
    int*       rlist= (int*)(ws + OFF_RLIST);
    double*    part = (double*)(ws + OFF_PART);
    u64*       pk1  = (u64*)(ws + OFF_PK1);
    float*     pv2  = (float*)(ws + OFF_PV2);
    _Float16*  z16  = (_Float16*)(ws + OFF_Z16);
    _Float16*  c16h = (_Float16*)(ws + OFF_CB16);
    u64*       rmin = pk1;   // first 256 KB of pk1 reused after detect

    hipMemsetAsync(rcnt, 0, 128, stream);
    rownorm256_np<<<NTOK / 256, 256, 0, stream>>>(z, An, NTOK);
    rownorm256_np<<<KCB / 256, 256, 0, stream>>>(cb, Cn, KCB);
    conv_z16<<<256 * 8, 128, 0, stream>>>(z, z16);
    conv_cb16h<<<32 * 8, 256, 0, stream>>>(cb, c16h);
    vq_mfma_top2<<<4096, 256, 0, stream>>>(z16, c16h, An, Cn, pk1, pv2);
    vq_detect<<<NTOK / 256, 256, 0, stream>>>(pk1, pv2, ids, rcnt, rlist);
    hipMemsetAsync(rmin, 0xFF, (size_t)NTOK * sizeof(u64), stream);  // after detect
    vq_rescue2<<<2048, 256, 0, stream>>>(z, cb, An, Cn, rcnt, rlist, rmin);
    vq_rescue_apply<<<32, 256, 0, stream>>>(rcnt, rlist, rmin, ids);
    vq_finalize_ids<<<NTOK / 16, 256, 0, stream>>>(z, cb, ids, out, part);
    vq_loss_write<<<1, 256, 0, stream>>>(part, out);
  } else {
    // R3 fallback (needs ~2.26 MB)
    float*  An = (float*)(ws);
    float*  Cn = (float*)(ws + 131072);
    float*  pv = (float*)(ws + 163840);
    int*    pk = (int*)(ws + 1212416);
    double* loss = (double*)(ws + 2260992);
    hipMemsetAsync(loss, 0, sizeof(double), stream);
    rownorm256_np<<<NTOK / 256, 256, 0, stream>>>(z, An, NTOK);
    rownorm256_np<<<KCB / 256, 256, 0, stream>>>(cb, Cn, KCB);
    vq_argmin_kernel<<<(NTOK / TT) * NCHUNK, 256, 0, stream>>>(z, cb, An, Cn, pv, pk);
    vq_finalize<<<NTOK / 4, 256, 0, stream>>>(z, cb, pv, pk, out, loss);
    vq_loss_write_fb<<<1, 1, 0, stream>>>(loss, out);
  }
}

// Round 21
// 566.908 us; speedup vs baseline: 1.2653x; 1.0471x over previous
//
#include <hip/hip_runtime.h>
#include <math.h>

#define NTOK 32768
#define DIM 256
#define KCB 8192
#define RESCUE_TAU 4e-3f

typedef _Float16 half8 __attribute__((ext_vector_type(8)));
typedef float f32x4 __attribute__((ext_vector_type(4)));
typedef unsigned long long u64;
typedef unsigned int u32;

// ---------------- fast-path ws layout (bytes) ----------------
#define OFF_AN    0ull
#define OFF_CN    131072ull
#define OFF_IDS   163840ull
#define OFF_RCNT  294912ull
#define OFF_RLIST 295040ull
#define OFF_PART  426112ull      // 2048 doubles
#define OFF_PK1   442496ull      // u64 [32768][8]; first 256KB reused as rmin[]
#define OFF_PV2   2539648ull     // f32 [32768][8]
#define OFF_Z16   3588224ull     // [256 tile][8 ks][128 row][64 halves swz]
#define OFF_CB16  37142656ull    // [32 tile][8 ks][256 row][64 halves swz]
#define WS_NEED   45531264ull

#define GLOAD_LDS16(gp, lp) __builtin_amdgcn_global_load_lds( \
    (const __attribute__((address_space(1))) void*)(gp), \
    (__attribute__((address_space(3))) void*)(lp), 16, 0, 0)

static __device__ __forceinline__ u64 umin64(u64 a, u64 b) { return a < b ? a : b; }
static __device__ __forceinline__ u64 umax64(u64 a, u64 b) { return a < b ? b : a; }

// ---- numpy-pairwise ||row||^2 body (bitwise np.sum(x*x,axis=1)) ----------
static __device__ __forceinline__ float rownorm_np_body(const float* __restrict__ p) {
  float blk[2];
#pragma unroll
  for (int b = 0; b < 2; ++b) {
    const float* a = p + b * 128;
    float rr[8];
#pragma unroll
    for (int j = 0; j < 8; ++j) rr[j] = __fmul_rn(a[j], a[j]);
    for (int i = 8; i < 128; i += 8) {
#pragma unroll
      for (int j = 0; j < 8; ++j)
        rr[j] = __fadd_rn(rr[j], __fmul_rn(a[i + j], a[i + j]));
    }
    float s01 = __fadd_rn(rr[0], rr[1]);
    float s23 = __fadd_rn(rr[2], rr[3]);
    float s45 = __fadd_rn(rr[4], rr[5]);
    float s67 = __fadd_rn(rr[6], rr[7]);
    blk[b] = __fadd_rn(__fadd_rn(s01, s23), __fadd_rn(s45, s67));
  }
  return __fadd_rn(blk[0], blk[1]);
}

// fused: one launch computes An (z rows) and Cn (cb rows)
__global__ __launch_bounds__(256)
void rownorm_both(const float* __restrict__ z, const float* __restrict__ cb,
                  float* __restrict__ An, float* __restrict__ Cn) {
  int r = blockIdx.x * 256 + threadIdx.x;
  if (r < NTOK) An[r] = rownorm_np_body(z + (size_t)r * DIM);
  else          Cn[r - NTOK] = rownorm_np_body(cb + (size_t)(r - NTOK) * DIM);
}

// (standalone, kept for fallback path)
__global__ __launch_bounds__(256)
void rownorm256_np(const float* __restrict__ M, float* __restrict__ out, int rows) {
  int r = blockIdx.x * 256 + threadIdx.x;
  if (r >= rows) return;
  out[r] = rownorm_np_body(M + (size_t)r * DIM);
}

// ---- convert: fp32 -> scaled fp16 (hi,lo) pair, pre-swizzled tiled layout ----
__global__ __launch_bounds__(128)
void conv_z16(const float* __restrict__ z, _Float16* __restrict__ dst) {
  const int tile = blockIdx.x >> 3, ks = blockIdx.x & 7, row = threadIdx.x;
  const float* src = z + ((size_t)(tile * 128 + row)) * DIM + ks * 32;
  _Float16* d = dst + (u64)tile * 65536 + (u64)ks * 8192 + row * 64;
  const int rs = row & 7;
#pragma unroll
  for (int q = 0; q < 4; ++q) {
    half8 hv, lv;
#pragma unroll
    for (int j = 0; j < 8; ++j) {
      float f = src[q * 8 + j] * 64.0f;          // exact pow2 scale
      _Float16 h = (_Float16)f;                  // RNE
      float lf = f - (float)h;                   // exact
      hv[j] = h; lv[j] = (_Float16)lf;
    }
    *reinterpret_cast<half8*>(d + ((q ^ rs) * 8)) = hv;
    *reinterpret_cast<half8*>(d + (((q + 4) ^ rs) * 8)) = lv;
  }
}

__global__ __launch_bounds__(256)
void conv_cb16(const float* __restrict__ cb, _Float16* __restrict__ dst) {
  const int tile = blockIdx.x >> 3, ks = blockIdx.x & 7, row = threadIdx.x;
  const float* src = cb + ((size_t)(tile * 256 + row)) * DIM + ks * 32;
  _Float16* d = dst + (u64)tile * 131072 + (u64)ks * 16384 + row * 64;
  const int rs = row & 7;
#pragma unroll
  for (int q = 0; q < 4; ++q) {
    half8 hv, lv;
#pragma unroll
    for (int j = 0; j < 8; ++j) {
      float f = src[q * 8 + j] * 1024.0f;        // exact pow2 scale
      _Float16 h = (_Float16)f;
      float lf = f - (float)h;
      hv[j] = h; lv[j] = (_Float16)lf;
    }
    *reinterpret_cast<half8*>(d + ((q ^ rs) * 8)) = hv;
    *reinterpret_cast<half8*>(d + (((q + 4) ^ rs) * 8)) = lv;
  }
}

// ---- MFMA GEMM + per-LANE top-2, A(hi) register-resident, 2-pass ---------
// R17 optimum: A hi-only (Ah[8][2]=64 VGPR, total 84) at launch_bounds(256,3)
// -> 3 blocks/CU. Measured trade-space: 2 blocks (flipped split)=348us,
// 3 blocks (this)=307us, 4 blocks=VGPR clamp+spill. Occupancy > LDS traffic.
__global__ __launch_bounds__(256, 3)
void vq_mfma_top2(const _Float16* __restrict__ z16, const _Float16* __restrict__ cb16,
                  const float* __restrict__ An, const float* __restrict__ Cn,
                  u64* __restrict__ pk1, float* __restrict__ pv2) {
  __shared__ _Float16 Bs0[128 * 64];   // 16 KB
  __shared__ _Float16 Bs1[128 * 64];   // 16 KB
  __shared__ float    Cs[1024];        // 4 KB  (this cg's code norms)
  __shared__ u64      t2k[64][2];      // 1 KB
  __shared__ u32      t2v[64][2];      // 0.5 KB

  const int tid = threadIdx.x;
  const int lane = tid & 63, w = tid >> 6;
  const int wm = w >> 1, wn = w & 1;
  // XCD swizzle: grid 4096, 8 XCDs -> each XCD owns exactly one cgroup
  const int swz = (blockIdx.x & 7) * 512 + (blockIdx.x >> 3);
  const int cg = swz >> 9, rem = swz & 511;
  const int ttile = rem >> 1, thalf = rem & 1;
  const int laneM = lane & 15, laneK = lane >> 4;
  const _Float16* zt = z16 + (u64)ttile * 65536;

  // A-fragment per-lane offsets (HI plane only) rows thalf*64 .. +63
  int offA[2];
#pragma unroll
  for (int f = 0; f < 2; ++f) {
    int row = thalf * 64 + wm * 32 + f * 16 + laneM;
    offA[f] = row * 64 + ((laneK ^ (row & 7)) * 8);
  }
  int offBh[4], offBl[4];
#pragma unroll
  for (int g = 0; g < 4; ++g) {
    int row = wn * 64 + g * 16 + laneM;
    offBh[g] = row * 64 + ((laneK ^ (row & 7)) * 8);
    offBl[g] = row * 64 + (((laneK + 4) ^ (row & 7)) * 8);
  }

  // preload A hi fragments (8 ks x 2 half8 = 64 VGPR) -> registers, once
  half8 Ah[8][2];
#pragma unroll
  for (int ks = 0; ks < 8; ++ks)
#pragma unroll
    for (int f = 0; f < 2; ++f)
      Ah[ks][f] = *reinterpret_cast<const half8*>(zt + ks * 8192 + offA[f]);

  // token norms
  float Areg[2][4];
#pragma unroll
  for (int f = 0; f < 2; ++f) {
    float4 a4 = *reinterpret_cast<const float4*>(
        &An[ttile * 128 + thalf * 64 + wm * 32 + f * 16 + laneK * 4]);
    Areg[f][0] = a4.x; Areg[f][1] = a4.y; Areg[f][2] = a4.z; Areg[f][3] = a4.w;
  }
  {  // stage this cg's code norms into LDS
    float4 c4 = *reinterpret_cast<const float4*>(&Cn[cg * 1024 + tid * 4]);
    *reinterpret_cast<float4*>(&Cs[tid * 4]) = c4;
  }

  // per-lane top-2 state: 8 token-slots
  u32 v1b[8], v2b[8], c1v[8];
#pragma unroll
  for (int s = 0; s < 8; ++s) { v1b[s] = 0x7F800000u; v2b[s] = 0x7F800000u; c1v[s] = 0; }
  u32 codeSub = (u32)(cg * 1024 + wn * 64 + laneM);  // += 128 per sub

#define STAGE_B(s, Bd) do {                                                  \
    const int ns_ = (s) >> 3, nk_ = (s) & 7;                                 \
    const _Float16* sb_ = cb16 + (u64)(cg * 4 + (ns_ >> 1)) * 131072 +       \
                          (u64)nk_ * 16384 + (u64)(ns_ & 1) * 8192 + tid * 8;\
    GLOAD_LDS16(sb_,        &Bd[tid * 8]);                                   \
    GLOAD_LDS16(sb_ + 2048, &Bd[tid * 8 + 2048]);                            \
    GLOAD_LDS16(sb_ + 4096, &Bd[tid * 8 + 4096]);                            \
    GLOAD_LDS16(sb_ + 6144, &Bd[tid * 8 + 6144]);                            \
  } while (0)

// 2-pass: Ah(hi) x Bh + Ah(hi) x Bl  (16 MFMA per step)
#define COMPUTE_KS(kc, Bsrc) do {                                            \
    _Pragma("unroll")                                                        \
    for (int g_ = 0; g_ < 4; ++g_) {                                         \
      half8 bh = *reinterpret_cast<const half8*>(&Bsrc[offBh[g_]]);          \
      half8 bl = *reinterpret_cast<const half8*>(&Bsrc[offBl[g_]]);          \
      _Pragma("unroll")                                                      \
      for (int f_ = 0; f_ < 2; ++f_)                                         \
        acc[f_][g_] = __builtin_amdgcn_mfma_f32_16x16x32_f16(Ah[kc][f_], bh, acc[f_][g_], 0, 0, 0); \
      _Pragma("unroll")                                                      \
      for (int f_ = 0; f_ < 2; ++f_)                                         \
        acc[f_][g_] = __builtin_amdgcn_mfma_f32_16x16x32_f16(Ah[kc][f_], bl, acc[f_][g_], 0, 0, 0); \
    }                                                                        \
  } while (0)

  // prologue: stage step 0 into Bs0
  STAGE_B(0, Bs0);
  __syncthreads();   // Bs0 + Cs ready

  f32x4 acc[2][4];
#pragma unroll
  for (int f = 0; f < 2; ++f)
#pragma unroll
    for (int g = 0; g < 4; ++g) acc[f][g] = (f32x4){0.f, 0.f, 0.f, 0.f};

  for (int sub = 0; sub < 8; ++sub) {
#pragma unroll
    for (int ks = 0; ks < 8; ++ks) {
      const int step = sub * 8 + ks;
      if (step < 63) {
        if (ks & 1) STAGE_B(step + 1, Bs0);
        else        STAGE_B(step + 1, Bs1);
      }
      if (ks & 1) COMPUTE_KS(ks, Bs1);
      else        COMPUTE_KS(ks, Bs0);

      if (ks == 7) {  // sub complete: per-lane top-2 update
        const int cbase = sub * 128 + wn * 64 + laneM;
        float Cg[4];
#pragma unroll
        for (int g = 0; g < 4; ++g) Cg[g] = Cs[cbase + g * 16];
#pragma unroll
        for (int f = 0; f < 2; ++f) {
#pragma unroll
          for (int r = 0; r < 4; ++r) {
            const int sl = f * 4 + r;
            const float Ar = Areg[f][r];
#pragma unroll
            for (int g = 0; g < 4; ++g) {
              float p2 = __fmul_rn(acc[f][g][r], 0x1p-15f);   // 2*dot, exact pow2
              float t1 = __fsub_rn(Ar, p2);
              float t  = __fadd_rn(t1, Cg[g]);
              u32 tb = __float_as_uint(t);        // t>0 -> bit cmp == float cmp
              u32 code = codeSub + (u32)(g * 16);
              bool lt1 = tb < v1b[sl];
              bool lt2 = tb < v2b[sl];
              v2b[sl] = lt1 ? v1b[sl] : (lt2 ? tb : v2b[sl]);
              c1v[sl] = lt1 ? code : c1v[sl];
              v1b[sl] = lt1 ? tb : v1b[sl];
            }
          }
        }
        codeSub += 128;
#pragma unroll
        for (int f = 0; f < 2; ++f)
#pragma unroll
          for (int g = 0; g < 4; ++g) acc[f][g] = (f32x4){0.f, 0.f, 0.f, 0.f};
      }
      __syncthreads();   // staged buffer ready; all waves done reading cur
    }
  }

#undef STAGE_B
#undef COMPUTE_KS

  // final cross-lane (laneM) top-2 reduce, once per kernel
#pragma unroll
  for (int sl = 0; sl < 8; ++sl) {
#pragma unroll
    for (int d = 1; d < 16; d <<= 1) {
      u32 o1 = (u32)__shfl_xor((int)v1b[sl], d);
      u32 oc = (u32)__shfl_xor((int)c1v[sl], d);
      u32 o2 = (u32)__shfl_xor((int)v2b[sl], d);
      u64 k  = ((u64)v1b[sl] << 32) | c1v[sl];
      u64 ko = ((u64)o1 << 32) | oc;
      u32 loser = v1b[sl] < o1 ? o1 : v1b[sl];
      u32 nv2 = min(loser, min(v2b[sl], o2));
      u64 nk = umin64(k, ko);
      v1b[sl] = (u32)(nk >> 32); c1v[sl] = (u32)nk; v2b[sl] = nv2;
    }
  }
  if (laneM == 0) {
#pragma unroll
    for (int f = 0; f < 2; ++f)
#pragma unroll
      for (int r = 0; r < 4; ++r) {
        const int tloc = wm * 32 + f * 16 + laneK * 4 + r;
        const int sl = f * 4 + r;
        t2k[tloc][wn] = ((u64)v1b[sl] << 32) | c1v[sl];
        t2v[tloc][wn] = v2b[sl];
      }
  }
  __syncthreads();
  if (tid < 64) {
    u64 k0 = t2k[tid][0], k1 = t2k[tid][1];
    u32 va = t2v[tid][0], vb = t2v[tid][1];
    u64 K1 = umin64(k0, k1);
    u32 loser = (u32)(umax64(k0, k1) >> 32);
    u32 V2 = min(min(va, vb), loser);
    const int token = ttile * 128 + thalf * 64 + tid;
    pk1[(size_t)token * 8 + cg] = K1;
    pv2[(size_t)token * 8 + cg] = __uint_as_float(V2);
  }
}

// ---- detect: merge 8 cgroup top-2, write candidate ids, flag near-ties ----
__global__ __launch_bounds__(256)
void vq_detect(const u64* __restrict__ pk1, const float* __restrict__ pv2,
               int* __restrict__ ids, int* __restrict__ rcnt, int* __restrict__ rlist) {
  const int token = blockIdx.x * 256 + threadIdx.x;
  u64 K1 = pk1[(size_t)token * 8];
  float V2 = pv2[(size_t)token * 8];
#pragma unroll
  for (int c = 1; c < 8; ++c) {
    u64 k1 = pk1[(size_t)token * 8 + c];
    float v2 = pv2[(size_t)token * 8 + c];
    u64 n1 = (k1 < K1) ? k1 : K1;
    u64 hi = (k1 < K1) ? K1 : k1;
    float loser = __uint_as_float((unsigned)(hi >> 32));
    V2 = fminf(fminf(V2, v2), loser);
    K1 = n1;
  }
  ids[token] = (int)(K1 & 0xffffffffull);
  float d1 = __uint_as_float((unsigned)(K1 >> 32));
  if (V2 - d1 < RESCUE_TAU) {
    int p = atomicAdd(rcnt, 1);
    rlist[p] = token;
  }
}

// ---- rescue v2: 2-D (32-token batch x 32 code-chunks) exact rescan -------
__global__ __launch_bounds__(256)
void vq_rescue2(const float* __restrict__ z, const float* __restrict__ cb,
                const float* __restrict__ An, const float* __restrict__ Cn,
                const int* __restrict__ rcnt, const int* __restrict__ rlist,
                u64* __restrict__ rmin) {
  const int tid = threadIdx.x;
  const int total = *rcnt;
  if (total == 0) return;
  const int nb = (total + 31) >> 5;   // batches of 32 tokens
  for (int wi = blockIdx.x; wi < nb * 32; wi += gridDim.x) {
    const int batch = wi >> 5, chunk = wi & 31;
    const int base = batch * 32;
    const int np = min(32, total - base);
    int toks[32];
#pragma unroll
    for (int s = 0; s < 32; ++s)
      toks[s] = rlist[base + (s < np ? s : 0)];   // pad with valid token
    const int j = chunk * 256 + tid;
    const float4* crow = reinterpret_cast<const float4*>(cb + (size_t)j * DIM);
    float dots[32];
#pragma unroll
    for (int s = 0; s < 32; ++s) dots[s] = 0.f;
    for (int k4 = 0; k4 < 64; ++k4) {
      const float4 c4 = crow[k4];
#pragma unroll
      for (int s = 0; s < 32; ++s) {   // k ascending, exact R3 chain
        const float4 z4 = *reinterpret_cast<const float4*>(
            z + (size_t)toks[s] * DIM + k4 * 4);
        dots[s] = fmaf(z4.x, c4.x, dots[s]);
        dots[s] = fmaf(z4.y, c4.y, dots[s]);
        dots[s] = fmaf(z4.z, c4.z, dots[s]);
        dots[s] = fmaf(z4.w, c4.w, dots[s]);
      }
    }
    const float Cj = Cn[j];
#pragma unroll
    for (int s = 0; s < 32; ++s) {
      if (s < np) {
        float p2 = __fmul_rn(2.0f, dots[s]);
        float t1 = __fsub_rn(An[toks[s]], p2);
        float t  = __fadd_rn(t1, Cj);
        u64 key = ((u64)__float_as_uint(t) << 32) | (u64)j;
#pragma unroll
        for (int d = 1; d < 64; d <<= 1) {
          u64 o = __shfl_xor(key, d);
          key = o < key ? o : key;
        }
        if ((tid & 63) == 0) atomicMin(&rmin[toks[s]], key);
      }
    }
  }
}

// ---- rescue apply: commit rescued winners into ids ------------------------
__global__ __launch_bounds__(256)
void vq_rescue_apply(const int* __restrict__ rcnt, const int* __restrict__ rlist,
                     const u64* __restrict__ rmin, int* __restrict__ ids) {
  const int total = *rcnt;
  for (int i = blockIdx.x * 256 + threadIdx.x; i < total; i += gridDim.x * 256) {
    const int t = rlist[i];
    ids[t] = (int)(rmin[t] & 0xffffffffull);
  }
}

// ---- finalize: gather z_q, ids; block-reduced loss partials (no atomics) --
__global__ __launch_bounds__(256)
void vq_finalize_ids(const float* __restrict__ z, const float* __restrict__ cb,
                     const int* __restrict__ ids, float* __restrict__ out,
                     double* __restrict__ part) {
  __shared__ double sred[4];
  const int g64 = threadIdx.x >> 6, lane = threadIdx.x & 63;
  double s = 0.0;
#pragma unroll
  for (int i = 0; i < 4; ++i) {
    const int n = blockIdx.x * 16 + i * 4 + g64;
    const int bk = ids[n];
    const float4 c4 = *reinterpret_cast<const float4*>(&cb[(size_t)bk * DIM + lane * 4]);
    const float4 z4 = *reinterpret_cast<const float4*>(&z[(size_t)n * DIM + lane * 4]);
    *reinterpret_cast<float4*>(&out[(size_t)n * DIM + lane * 4]) = c4;
    float dx = __fsub_rn(c4.x, z4.x), dy = __fsub_rn(c4.y, z4.y);
    float dz = __fsub_rn(c4.z, z4.z), dw = __fsub_rn(c4.w, z4.w);
    s += (double)dx * dx + (double)dy * dy + (double)dz * dz + (double)dw * dw;
    if (lane == 0) out[(size_t)NTOK * DIM + n] = (float)bk;
  }
#pragma unroll
  for (int off = 32; off > 0; off >>= 1) s += __shfl_down(s, off);
  if (lane == 0) sred[g64] = s;
  __syncthreads();
  if (threadIdx.x == 0)
    part[blockIdx.x] = (sred[0] + sred[1]) + (sred[2] + sred[3]);
}

__global__ __launch_bounds__(256)
void vq_loss_write(const double* __restrict__ part, float* __restrict__ out) {
  __shared__ double red[256];
  double s = 0.0;
  for (int i = threadIdx.x; i < 2048; i += 256) s += part[i];
  red[threadIdx.x] = s;
  __syncthreads();
  for (int off = 128; off > 0; off >>= 1) {
    if (threadIdx.x < off) red[threadIdx.x] += red[threadIdx.x + off];
    __syncthreads();
  }
  if (threadIdx.x == 0)
    out[(size_t)NTOK * DIM + NTOK] =
        (float)(0.25 * red[0] / (double)((size_t)NTOK * DIM));
}

// ======================= R3 fallback path (ws too small) ==================
#define NCHUNK 8
#define CHUNK 1024
#define TT 128
#define CT 128
#define DC 32

__global__ __launch_bounds__(256)
void vq_argmin_kernel(const float* __restrict__ z, const float* __restrict__ cb,
                      const float* __restrict__ An, const float* __restrict__ Cn,
                      float* __restrict__ pv, int* __restrict__ pk) {
  __shared__ float zs[DC * TT];
  __shared__ float cs[DC * CT];
  const int tid = threadIdx.x;
  const int tx = tid & 15, ty = tid >> 4;
  const int chunk = blockIdx.x & 7;
  const int tile = blockIdx.x >> 3;
  const int base_t = tile * TT;
  const int base_k = chunk * CHUNK;
  float Areg[8];
#pragma unroll
  for (int i = 0; i < 8; ++i) Areg[i] = An[base_t + ty * 8 + i];
  float bestv[8]; int bestk[8];
#pragma unroll
  for (int i = 0; i < 8; ++i) { bestv[i] = INFINITY; bestk[i] = 0; }
  for (int st = 0; st < CHUNK / CT; ++st) {
    const int kb0 = base_k + st * CT;
    float acc[8][8];
#pragma unroll
    for (int i = 0; i < 8; ++i)
#pragma unroll
      for (int j = 0; j < 8; ++j) acc[i][j] = 0.f;
    for (int dc = 0; dc < DIM / DC; ++dc) {
      __syncthreads();
#pragma unroll
      for (int li = tid; li < DC * TT / 4; li += 256) {
        const int row = li >> 3;
        const int dv = li & 7;
        const int ibase = dv * 4 * 128 + (row ^ (dv << 2) ^ ((row & 32) >> 3));
        float4 v = *reinterpret_cast<const float4*>(
            &z[(size_t)(base_t + row) * DIM + dc * DC + dv * 4]);
        zs[ibase] = v.x; zs[ibase + 128] = v.y;
        zs[ibase + 256] = v.z; zs[ibase + 384] = v.w;
        float4 c = *reinterpret_cast<const float4*>(
            &cb[(size_t)(kb0 + row) * DIM + dc * DC + dv * 4]);
        cs[ibase] = c.x; cs[ibase + 128] = c.y;
        cs[ibase + 256] = c.z; cs[ibase + 384] = c.w;
      }
      __syncthreads();
#pragma unroll
      for (int dd = 0; dd < DC / 4; ++dd) {
        const int s1 = dd << 2;
        const float* zp0 = &zs[dd * 4 * 128 + ((ty * 8) ^ s1 ^ (ty & 4))];
        const float* zp1 = &zs[dd * 4 * 128 + ((ty * 8 + 4) ^ s1 ^ (ty & 4))];
        const float* cp0 = &cs[dd * 4 * 128 + ((tx * 8) ^ s1 ^ (tx & 4))];
        const float* cp1 = &cs[dd * 4 * 128 + ((tx * 8 + 4) ^ s1 ^ (tx & 4))];
#pragma unroll
        for (int q = 0; q < 4; ++q) {
          const float4 za  = *reinterpret_cast<const float4*>(zp0 + q * 128);
          const float4 zb  = *reinterpret_cast<const float4*>(zp1 + q * 128);
          const float4 ca  = *reinterpret_cast<const float4*>(cp0 + q * 128);
          const float4 cbv = *reinterpret_cast<const float4*>(cp1 + q * 128);
          const float zv[8] = {za.x, za.y, za.z, za.w, zb.x, zb.y, zb.z, zb.w};
          const float cv[8] = {ca.x, ca.y, ca.z, ca.w, cbv.x, cbv.y, cbv.z, cbv.w};
#pragma unroll
          for (int i = 0; i < 8; ++i)
#pragma unroll
            for (int j = 0; j < 8; ++j)
              acc[i][j] = fmaf(zv[i], cv[j], acc[i][j]);
        }
      }
    }
#pragma unroll
    for (int j = 0; j < 8; ++j) {
      const int klocal = st * CT + tx * 8 + j;
      const float Ck = Cn[base_k + klocal];
#pragma unroll
      for (int i = 0; i < 8; ++i) {
        float p2 = __fmul_rn(2.0f, acc[i][j]);
        float t1 = __fsub_rn(Areg[i], p2);
        float t  = __fadd_rn(t1, Ck);
        if (t < bestv[i]) { bestv[i] = t; bestk[i] = klocal; }
      }
    }
  }
  __syncthreads();
  float (*mv)[16] = reinterpret_cast<float(*)[16]>(zs);
  int   (*mk)[16] = reinterpret_cast<int(*)[16]>(zs + TT * 16);
#pragma unroll
  for (int i = 0; i < 8; ++i) { mv[ty * 8 + i][tx] = bestv[i]; mk[ty * 8 + i][tx] = bestk[i]; }
  __syncthreads();
  if (tid < TT) {
    float bv = mv[tid][0]; int bk = mk[tid][0];
#pragma unroll
    for (int x = 1; x < 16; ++x) {
      float v = mv[tid][x]; int k = mk[tid][x];
      if (v < bv || (v == bv && k < bk)) { bv = v; bk = k; }
    }
    size_t idx = (size_t)(base_t + tid) * NCHUNK + chunk;
    pv[idx] = bv;
    pk[idx] = base_k + bk;
  }
}

__global__ __launch_bounds__(256)
void vq_finalize(const float* __restrict__ z, const float* __restrict__ cb,
                 const float* __restrict__ pv, const int* __restrict__ pk,
                 float* __restrict__ out, double* __restrict__ loss_acc) {
  const int n = blockIdx.x * 4 + (threadIdx.x >> 6);
  const int lane = threadIdx.x & 63;
  float bv = INFINITY; int bk = 0;
#pragma unroll
  for (int c = 0; c < NCHUNK; ++c) {
    float v = pv[(size_t)n * NCHUNK + c];
    int k = pk[(size_t)n * NCHUNK + c];
    if (v < bv || (v == bv && k < bk)) { bv = v; bk = k; }
  }
  const float4 c4 = *reinterpret_cast<const float4*>(&cb[(size_t)bk * DIM + lane * 4]);
  const float4 z4 = *reinterpret_cast<const float4*>(&z[(size_t)n * DIM + lane * 4]);
  *reinterpret_cast<float4*>(&out[(size_t)n * DIM + lane * 4]) = c4;
  float dx = __fsub_rn(c4.x, z4.x), dy = __fsub_rn(c4.y, z4.y);
  float dz = __fsub_rn(c4.z, z4.z), dw = __fsub_rn(c4.w, z4.w);
  double s = (double)dx * dx + (double)dy * dy + (double)dz * dz + (double)dw * dw;
#pragma unroll
  for (int off = 32; off > 0; off >>= 1) s += __shfl_down(s, off);
  if (lane == 0) {
    out[(size_t)NTOK * DIM + n] = (float)bk;
    atomicAdd(loss_acc, s);
  }
}

__global__ void vq_loss_write_fb(const double* __restrict__ loss_acc, float* __restrict__ out) {
  out[(size_t)NTOK * DIM + NTOK] = (float)(0.25 * (*loss_acc) / (double)((size_t)NTOK * DIM));
}

// ==========================================================================
extern "C" void kernel_launch(void* const* d_in, const int* in_sizes, int n_in,
                              void* d_out, int out_size, void* d_ws, size_t ws_size,
                              hipStream_t stream) {
  const float* z  = (const float*)d_in[0];
  const float* cb = (const float*)d_in[1];
  float* out = (float*)d_out;
  char* ws = (char*)d_ws;

  if (ws_size >= WS_NEED) {
    float*     An   = (float*)(ws + OFF_AN);
    float*     Cn   = (float*)(ws + OFF_CN);
    int*       ids  = (int*)(ws + OFF_IDS);
    int*       rcnt = (int*)(ws + OFF_RCNT);
    int*       rlist= (int*)(ws + OFF_RLIST);
    double*    part = (double*)(ws + OFF_PART);
    u64*       pk1  = (u64*)(ws + OFF_PK1);
    float*     pv2  = (float*)(ws + OFF_PV2);
    _Float16*  z16  = (_Float16*)(ws + OFF_Z16);
    _Float16*  c16  = (_Float16*)(ws + OFF_CB16);
    u64*       rmin = pk1;   // first 256 KB of pk1 reused after detect

    hipMemsetAsync(rcnt, 0, 128, stream);
    rownorm_both<<<(NTOK + KCB) / 256, 256, 0, stream>>>(z, cb, An, Cn);
    conv_z16<<<256 * 8, 128, 0, stream>>>(z, z16);
    conv_cb16<<<32 * 8, 256, 0, stream>>>(cb, c16);
    vq_mfma_top2<<<4096, 256, 0, stream>>>(z16, c16, An, Cn, pk1, pv2);
    vq_detect<<<NTOK / 256, 256, 0, stream>>>(pk1, pv2, ids, rcnt, rlist);
    hipMemsetAsync(rmin, 0xFF, (size_t)NTOK * sizeof(u64), stream);  // after detect
    vq_rescue2<<<2048, 256, 0, stream>>>(z, cb, An, Cn, rcnt, rlist, rmin);
    vq_rescue_apply<<<32, 256, 0, stream>>>(rcnt, rlist, rmin, ids);
    vq_finalize_ids<<<NTOK / 16, 256, 0, stream>>>(z, cb, ids, out, part);
    vq_loss_write<<<1, 256, 0, stream>>>(part, out);
  } else {
    // R3 fallback (needs ~2.26 MB)
    float*  An = (float*)(ws);
    float*  Cn = (float*)(ws + 131072);
    float*  pv = (float*)(ws + 163840);
    int*    pk = (int*)(ws + 1212416);
    double* loss = (double*)(ws + 2260992);
    hipMemsetAsync(loss, 0, sizeof(double), stream);
    rownorm256_np<<<NTOK / 256, 256, 0, stream>>>(z, An, NTOK);
    rownorm256_np<<<KCB / 256, 256, 0, stream>>>(cb, Cn, KCB);
    vq_argmin_kernel<<<(NTOK / TT) * NCHUNK, 256, 0, stream>>>(z, cb, An, Cn, pv, pk);
    vq_finalize<<<NTOK / 4, 256, 0, stream>>>(z, cb, pv, pk, out, loss);
    vq_loss_write_fb<<<1, 1, 0, stream>>>(loss, out);
  }
}

// Round 22
// 559.648 us; speedup vs baseline: 1.2817x; 1.0130x over previous
//
#include <hip/hip_runtime.h>
#include <math.h>

#define NTOK 32768
#define DIM 256
#define KCB 8192
#define RESCUE_TAU 4e-3f

typedef _Float16 half8 __attribute__((ext_vector_type(8)));
typedef float f32x4 __attribute__((ext_vector_type(4)));
typedef unsigned long long u64;
typedef unsigned int u32;

// ---------------- fast-path ws layout (bytes) ----------------
#define OFF_AN    0ull
#define OFF_CN    131072ull
#define OFF_IDS   163840ull
#define OFF_RCNT  294912ull
#define OFF_RLIST 295040ull
#define OFF_PART  426112ull      // 2048 doubles
#define OFF_PK1   442496ull      // u64 [32768][8]; first 256KB reused as rmin[]
#define OFF_PV2   2539648ull     // f32 [32768][8]
#define OFF_Z16   3588224ull     // [256 tile][8 ks][128 row][64 halves swz]
#define OFF_CB16  37142656ull    // [32 tile][8 ks][256 row][64 halves swz]
#define WS_NEED   45531264ull

#define GLOAD_LDS16(gp, lp) __builtin_amdgcn_global_load_lds( \
    (const __attribute__((address_space(1))) void*)(gp), \
    (__attribute__((address_space(3))) void*)(lp), 16, 0, 0)

static __device__ __forceinline__ u64 umin64(u64 a, u64 b) { return a < b ? a : b; }
static __device__ __forceinline__ u64 umax64(u64 a, u64 b) { return a < b ? b : a; }

// ---- numpy-pairwise ||row||^2 body (bitwise np.sum(x*x,axis=1)) ----------
static __device__ __forceinline__ float rownorm_np_body(const float* __restrict__ p) {
  float blk[2];
#pragma unroll
  for (int b = 0; b < 2; ++b) {
    const float* a = p + b * 128;
    float rr[8];
#pragma unroll
    for (int j = 0; j < 8; ++j) rr[j] = __fmul_rn(a[j], a[j]);
    for (int i = 8; i < 128; i += 8) {
#pragma unroll
      for (int j = 0; j < 8; ++j)
        rr[j] = __fadd_rn(rr[j], __fmul_rn(a[i + j], a[i + j]));
    }
    float s01 = __fadd_rn(rr[0], rr[1]);
    float s23 = __fadd_rn(rr[2], rr[3]);
    float s45 = __fadd_rn(rr[4], rr[5]);
    float s67 = __fadd_rn(rr[6], rr[7]);
    blk[b] = __fadd_rn(__fadd_rn(s01, s23), __fadd_rn(s45, s67));
  }
  return __fadd_rn(blk[0], blk[1]);
}

// (standalone, kept for fallback path)
__global__ __launch_bounds__(256)
void rownorm256_np(const float* __restrict__ M, float* __restrict__ out, int rows) {
  int r = blockIdx.x * 256 + threadIdx.x;
  if (r >= rows) return;
  out[r] = rownorm_np_body(M + (size_t)r * DIM);
}

// ---- fused preprocessing: one launch = conv_z16 + conv_cb16 + both norms --
// Grid 1440 x 256. Branch is wave-uniform (blockIdx ranges); each sub-body
// is VERBATIM from the verified R21 kernels, only the (block,thread) ->
// (tile,ks,row) map changes for conv_z16 (2048x128 -> 1024x256, bijective:
// ks = (b&3)*2 | tid>>7, row = tid&127).
__global__ __launch_bounds__(256)
void vq_prep(const float* __restrict__ z, const float* __restrict__ cb,
             float* __restrict__ An, float* __restrict__ Cn,
             _Float16* __restrict__ z16, _Float16* __restrict__ c16) {
  const int b = blockIdx.x, tid = threadIdx.x;
  if (b < 1024) {
    // conv_z16 part: z -> scaled fp16 (hi,lo), pre-swizzled
    const int tile = b >> 2, ks = ((b & 3) << 1) | (tid >> 7), row = tid & 127;
    const float* src = z + ((size_t)(tile * 128 + row)) * DIM + ks * 32;
    _Float16* d = z16 + (u64)tile * 65536 + (u64)ks * 8192 + row * 64;
    const int rs = row & 7;
#pragma unroll
    for (int q = 0; q < 4; ++q) {
      half8 hv, lv;
#pragma unroll
      for (int j = 0; j < 8; ++j) {
        float f = src[q * 8 + j] * 64.0f;        // exact pow2 scale
        _Float16 h = (_Float16)f;                // RNE
        float lf = f - (float)h;                 // exact
        hv[j] = h; lv[j] = (_Float16)lf;
      }
      *reinterpret_cast<half8*>(d + ((q ^ rs) * 8)) = hv;
      *reinterpret_cast<half8*>(d + (((q + 4) ^ rs) * 8)) = lv;
    }
  } else if (b < 1280) {
    // conv_cb16 part
    const int b2 = b - 1024;
    const int tile = b2 >> 3, ks = b2 & 7, row = tid;
    const float* src = cb + ((size_t)(tile * 256 + row)) * DIM + ks * 32;
    _Float16* d = c16 + (u64)tile * 131072 + (u64)ks * 16384 + row * 64;
    const int rs = row & 7;
#pragma unroll
    for (int q = 0; q < 4; ++q) {
      half8 hv, lv;
#pragma unroll
      for (int j = 0; j < 8; ++j) {
        float f = src[q * 8 + j] * 1024.0f;      // exact pow2 scale
        _Float16 h = (_Float16)f;
        float lf = f - (float)h;
        hv[j] = h; lv[j] = (_Float16)lf;
      }
      *reinterpret_cast<half8*>(d + ((q ^ rs) * 8)) = hv;
      *reinterpret_cast<half8*>(d + (((q + 4) ^ rs) * 8)) = lv;
    }
  } else {
    // rownorm part: r in [0, NTOK+KCB)
    const int r = (b - 1280) * 256 + tid;
    if (r < NTOK) An[r] = rownorm_np_body(z + (size_t)r * DIM);
    else          Cn[r - NTOK] = rownorm_np_body(cb + (size_t)(r - NTOK) * DIM);
  }
}

// ---- MFMA GEMM + per-LANE top-2, A(hi) register-resident, 2-pass ---------
// R17 optimum: A hi-only (Ah[8][2]=64 VGPR, total 84) at launch_bounds(256,3)
// -> 3 blocks/CU. Measured trade-space: 2 blocks (flipped split)=348us,
// 3 blocks (this)=307us, 4 blocks=VGPR clamp+spill. Occupancy > LDS traffic.
__global__ __launch_bounds__(256, 3)
void vq_mfma_top2(const _Float16* __restrict__ z16, const _Float16* __restrict__ cb16,
                  const float* __restrict__ An, const float* __restrict__ Cn,
                  u64* __restrict__ pk1, float* __restrict__ pv2) {
  __shared__ _Float16 Bs0[128 * 64];   // 16 KB
  __shared__ _Float16 Bs1[128 * 64];   // 16 KB
  __shared__ float    Cs[1024];        // 4 KB  (this cg's code norms)
  __shared__ u64      t2k[64][2];      // 1 KB
  __shared__ u32      t2v[64][2];      // 0.5 KB

  const int tid = threadIdx.x;
  const int lane = tid & 63, w = tid >> 6;
  const int wm = w >> 1, wn = w & 1;
  // XCD swizzle: grid 4096, 8 XCDs -> each XCD owns exactly one cgroup
  const int swz = (blockIdx.x & 7) * 512 + (blockIdx.x >> 3);
  const int cg = swz >> 9, rem = swz & 511;
  const int ttile = rem >> 1, thalf = rem & 1;
  const int laneM = lane & 15, laneK = lane >> 4;
  const _Float16* zt = z16 + (u64)ttile * 65536;

  // A-fragment per-lane offsets (HI plane only) rows thalf*64 .. +63
  int offA[2];
#pragma unroll
  for (int f = 0; f < 2; ++f) {
    int row = thalf * 64 + wm * 32 + f * 16 + laneM;
    offA[f] = row * 64 + ((laneK ^ (row & 7)) * 8);
  }
  int offBh[4], offBl[4];
#pragma unroll
  for (int g = 0; g < 4; ++g) {
    int row = wn * 64 + g * 16 + laneM;
    offBh[g] = row * 64 + ((laneK ^ (row & 7)) * 8);
    offBl[g] = row * 64 + (((laneK + 4) ^ (row & 7)) * 8);
  }

  // preload A hi fragments (8 ks x 2 half8 = 64 VGPR) -> registers, once
  half8 Ah[8][2];
#pragma unroll
  for (int ks = 0; ks < 8; ++ks)
#pragma unroll
    for (int f = 0; f < 2; ++f)
      Ah[ks][f] = *reinterpret_cast<const half8*>(zt + ks * 8192 + offA[f]);

  // token norms
  float Areg[2][4];
#pragma unroll
  for (int f = 0; f < 2; ++f) {
    float4 a4 = *reinterpret_cast<const float4*>(
        &An[ttile * 128 + thalf * 64 + wm * 32 + f * 16 + laneK * 4]);
    Areg[f][0] = a4.x; Areg[f][1] = a4.y; Areg[f][2] = a4.z; Areg[f][3] = a4.w;
  }
  {  // stage this cg's code norms into LDS
    float4 c4 = *reinterpret_cast<const float4*>(&Cn[cg * 1024 + tid * 4]);
    *reinterpret_cast<float4*>(&Cs[tid * 4]) = c4;
  }

  // per-lane top-2 state: 8 token-slots
  u32 v1b[8], v2b[8], c1v[8];
#pragma unroll
  for (int s = 0; s < 8; ++s) { v1b[s] = 0x7F800000u; v2b[s] = 0x7F800000u; c1v[s] = 0; }
  u32 codeSub = (u32)(cg * 1024 + wn * 64 + laneM);  // += 128 per sub

#define STAGE_B(s, Bd) do {                                                  \
    const int ns_ = (s) >> 3, nk_ = (s) & 7;                                 \
    const _Float16* sb_ = cb16 + (u64)(cg * 4 + (ns_ >> 1)) * 131072 +       \
                          (u64)nk_ * 16384 + (u64)(ns_ & 1) * 8192 + tid * 8;\
    GLOAD_LDS16(sb_,        &Bd[tid * 8]);                                   \
    GLOAD_LDS16(sb_ + 2048, &Bd[tid * 8 + 2048]);                            \
    GLOAD_LDS16(sb_ + 4096, &Bd[tid * 8 + 4096]);                            \
    GLOAD_LDS16(sb_ + 6144, &Bd[tid * 8 + 6144]);                            \
  } while (0)

// 2-pass: Ah(hi) x Bh + Ah(hi) x Bl  (16 MFMA per step)
#define COMPUTE_KS(kc, Bsrc) do {                                            \
    _Pragma("unroll")                                                        \
    for (int g_ = 0; g_ < 4; ++g_) {                                         \
      half8 bh = *reinterpret_cast<const half8*>(&Bsrc[offBh[g_]]);          \
      half8 bl = *reinterpret_cast<const half8*>(&Bsrc[offBl[g_]]);          \
      _Pragma("unroll")                                                      \
      for (int f_ = 0; f_ < 2; ++f_)                                         \
        acc[f_][g_] = __builtin_amdgcn_mfma_f32_16x16x32_f16(Ah[kc][f_], bh, acc[f_][g_], 0, 0, 0); \
      _Pragma("unroll")                                                      \
      for (int f_ = 0; f_ < 2; ++f_)                                         \
        acc[f_][g_] = __builtin_amdgcn_mfma_f32_16x16x32_f16(Ah[kc][f_], bl, acc[f_][g_], 0, 0, 0); \
    }                                                                        \
  } while (0)

  // prologue: stage step 0 into Bs0
  STAGE_B(0, Bs0);
  __syncthreads();   // Bs0 + Cs ready

  f32x4 acc[2][4];
#pragma unroll
  for (int f = 0; f < 2; ++f)
#pragma unroll
    for (int g = 0; g < 4; ++g) acc[f][g] = (f32x4){0.f, 0.f, 0.f, 0.f};

  for (int sub = 0; sub < 8; ++sub) {
#pragma unroll
    for (int ks = 0; ks < 8; ++ks) {
      const int step = sub * 8 + ks;
      if (step < 63) {
        if (ks & 1) STAGE_B(step + 1, Bs0);
        else        STAGE_B(step + 1, Bs1);
      }
      if (ks & 1) COMPUTE_KS(ks, Bs1);
      else        COMPUTE_KS(ks, Bs0);

      if (ks == 7) {  // sub complete: per-lane top-2 update
        const int cbase = sub * 128 + wn * 64 + laneM;
        float Cg[4];
#pragma unroll
        for (int g = 0; g < 4; ++g) Cg[g] = Cs[cbase + g * 16];
#pragma unroll
        for (int f = 0; f < 2; ++f) {
#pragma unroll
          for (int r = 0; r < 4; ++r) {
            const int sl = f * 4 + r;
            const float Ar = Areg[f][r];
#pragma unroll
            for (int g = 0; g < 4; ++g) {
              float p2 = __fmul_rn(acc[f][g][r], 0x1p-15f);   // 2*dot, exact pow2
              float t1 = __fsub_rn(Ar, p2);
              float t  = __fadd_rn(t1, Cg[g]);
              u32 tb = __float_as_uint(t);        // t>0 -> bit cmp == float cmp
              u32 code = codeSub + (u32)(g * 16);
              bool lt1 = tb < v1b[sl];
              bool lt2 = tb < v2b[sl];
              v2b[sl] = lt1 ? v1b[sl] : (lt2 ? tb : v2b[sl]);
              c1v[sl] = lt1 ? code : c1v[sl];
              v1b[sl] = lt1 ? tb : v1b[sl];
            }
          }
        }
        codeSub += 128;
#pragma unroll
        for (int f = 0; f < 2; ++f)
#pragma unroll
          for (int g = 0; g < 4; ++g) acc[f][g] = (f32x4){0.f, 0.f, 0.f, 0.f};
      }
      __syncthreads();   // staged buffer ready; all waves done reading cur
    }
  }

#undef STAGE_B
#undef COMPUTE_KS

  // final cross-lane (laneM) top-2 reduce, once per kernel
#pragma unroll
  for (int sl = 0; sl < 8; ++sl) {
#pragma unroll
    for (int d = 1; d < 16; d <<= 1) {
      u32 o1 = (u32)__shfl_xor((int)v1b[sl], d);
      u32 oc = (u32)__shfl_xor((int)c1v[sl], d);
      u32 o2 = (u32)__shfl_xor((int)v2b[sl], d);
      u64 k  = ((u64)v1b[sl] << 32) | c1v[sl];
      u64 ko = ((u64)o1 << 32) | oc;
      u32 loser = v1b[sl] < o1 ? o1 : v1b[sl];
      u32 nv2 = min(loser, min(v2b[sl], o2));
      u64 nk = umin64(k, ko);
      v1b[sl] = (u32)(nk >> 32); c1v[sl] = (u32)nk; v2b[sl] = nv2;
    }
  }
  if (laneM == 0) {
#pragma unroll
    for (int f = 0; f < 2; ++f)
#pragma unroll
      for (int r = 0; r < 4; ++r) {
        const int tloc = wm * 32 + f * 16 + laneK * 4 + r;
        const int sl = f * 4 + r;
        t2k[tloc][wn] = ((u64)v1b[sl] << 32) | c1v[sl];
        t2v[tloc][wn] = v2b[sl];
      }
  }
  __syncthreads();
  if (tid < 64) {
    u64 k0 = t2k[tid][0], k1 = t2k[tid][1];
    u32 va = t2v[tid][0], vb = t2v[tid][1];
    u64 K1 = umin64(k0, k1);
    u32 loser = (u32)(umax64(k0, k1) >> 32);
    u32 V2 = min(min(va, vb), loser);
    const int token = ttile * 128 + thalf * 64 + tid;
    pk1[(size_t)token * 8 + cg] = K1;
    pv2[(size_t)token * 8 + cg] = __uint_as_float(V2);
  }
}

// ---- detect: merge 8 cgroup top-2, write candidate ids, flag near-ties ----
__global__ __launch_bounds__(256)
void vq_detect(const u64* __restrict__ pk1, const float* __restrict__ pv2,
               int* __restrict__ ids, int* __restrict__ rcnt, int* __restrict__ rlist) {
  const int token = blockIdx.x * 256 + threadIdx.x;
  u64 K1 = pk1[(size_t)token * 8];
  float V2 = pv2[(size_t)token * 8];
#pragma unroll
  for (int c = 1; c < 8; ++c) {
    u64 k1 = pk1[(size_t)token * 8 + c];
    float v2 = pv2[(size_t)token * 8 + c];
    u64 n1 = (k1 < K1) ? k1 : K1;
    u64 hi = (k1 < K1) ? K1 : k1;
    float loser = __uint_as_float((unsigned)(hi >> 32));
    V2 = fminf(fminf(V2, v2), loser);
    K1 = n1;
  }
  ids[token] = (int)(K1 & 0xffffffffull);
  float d1 = __uint_as_float((unsigned)(K1 >> 32));
  if (V2 - d1 < RESCUE_TAU) {
    int p = atomicAdd(rcnt, 1);
    rlist[p] = token;
  }
}

// ---- rescue v2: 2-D (32-token batch x 32 code-chunks) exact rescan -------
__global__ __launch_bounds__(256)
void vq_rescue2(const float* __restrict__ z, const float* __restrict__ cb,
                const float* __restrict__ An, const float* __restrict__ Cn,
                const int* __restrict__ rcnt, const int* __restrict__ rlist,
                u64* __restrict__ rmin) {
  const int tid = threadIdx.x;
  const int total = *rcnt;
  if (total == 0) return;
  const int nb = (total + 31) >> 5;   // batches of 32 tokens
  for (int wi = blockIdx.x; wi < nb * 32; wi += gridDim.x) {
    const int batch = wi >> 5, chunk = wi & 31;
    const int base = batch * 32;
    const int np = min(32, total - base);
    int toks[32];
#pragma unroll
    for (int s = 0; s < 32; ++s)
      toks[s] = rlist[base + (s < np ? s : 0)];   // pad with valid token
    const int j = chunk * 256 + tid;
    const float4* crow = reinterpret_cast<const float4*>(cb + (size_t)j * DIM);
    float dots[32];
#pragma unroll
    for (int s = 0; s < 32; ++s) dots[s] = 0.f;
    for (int k4 = 0; k4 < 64; ++k4) {
      const float4 c4 = crow[k4];
#pragma unroll
      for (int s = 0; s < 32; ++s) {   // k ascending, exact R3 chain
        const float4 z4 = *reinterpret_cast<const float4*>(
            z + (size_t)toks[s] * DIM + k4 * 4);
        dots[s] = fmaf(z4.x, c4.x, dots[s]);
        dots[s] = fmaf(z4.y, c4.y, dots[s]);
        dots[s] = fmaf(z4.z, c4.z, dots[s]);
        dots[s] = fmaf(z4.w, c4.w, dots[s]);
      }
    }
    const float Cj = Cn[j];
#pragma unroll
    for (int s = 0; s < 32; ++s) {
      if (s < np) {
        float p2 = __fmul_rn(2.0f, dots[s]);
        float t1 = __fsub_rn(An[toks[s]], p2);
        float t  = __fadd_rn(t1, Cj);
        u64 key = ((u64)__float_as_uint(t) << 32) | (u64)j;
#pragma unroll
        for (int d = 1; d < 64; d <<= 1) {
          u64 o = __shfl_xor(key, d);
          key = o < key ? o : key;
        }
        if ((tid & 63) == 0) atomicMin(&rmin[toks[s]], key);
      }
    }
  }
}

// ---- rescue apply: commit rescued winners into ids ------------------------
__global__ __launch_bounds__(256)
void vq_rescue_apply(const int* __restrict__ rcnt, const int* __restrict__ rlist,
                     const u64* __restrict__ rmin, int* __restrict__ ids) {
  const int total = *rcnt;
  for (int i = blockIdx.x * 256 + threadIdx.x; i < total; i += gridDim.x * 256) {
    const int t = rlist[i];
    ids[t] = (int)(rmin[t] & 0xffffffffull);
  }
}

// ---- finalize: gather z_q, ids; block-reduced loss partials (no atomics) --
__global__ __launch_bounds__(256)
void vq_finalize_ids(const float* __restrict__ z, const float* __restrict__ cb,
                     const int* __restrict__ ids, float* __restrict__ out,
                     double* __restrict__ part) {
  __shared__ double sred[4];
  const int g64 = threadIdx.x >> 6, lane = threadIdx.x & 63;
  double s = 0.0;
#pragma unroll
  for (int i = 0; i < 4; ++i) {
    const int n = blockIdx.x * 16 + i * 4 + g64;
    const int bk = ids[n];
    const float4 c4 = *reinterpret_cast<const float4*>(&cb[(size_t)bk * DIM + lane * 4]);
    const float4 z4 = *reinterpret_cast<const float4*>(&z[(size_t)n * DIM + lane * 4]);
    *reinterpret_cast<float4*>(&out[(size_t)n * DIM + lane * 4]) = c4;
    float dx = __fsub_rn(c4.x, z4.x), dy = __fsub_rn(c4.y, z4.y);
    float dz = __fsub_rn(c4.z, z4.z), dw = __fsub_rn(c4.w, z4.w);
    s += (double)dx * dx + (double)dy * dy + (double)dz * dz + (double)dw * dw;
    if (lane == 0) out[(size_t)NTOK * DIM + n] = (float)bk;
  }
#pragma unroll
  for (int off = 32; off > 0; off >>= 1) s += __shfl_down(s, off);
  if (lane == 0) sred[g64] = s;
  __syncthreads();
  if (threadIdx.x == 0)
    part[blockIdx.x] = (sred[0] + sred[1]) + (sred[2] + sred[3]);
}

__global__ __launch_bounds__(256)
void vq_loss_write(const double* __restrict__ part, float* __restrict__ out) {
  __shared__ double red[256];
  double s = 0.0;
  for (int i = threadIdx.x; i < 2048; i += 256) s += part[i];
  red[threadIdx.x] = s;
  __syncthreads();
  for (int off = 128; off > 0; off >>= 1) {
    if (threadIdx.x < off) red[threadIdx.x] += red[threadIdx.x + off];
    __syncthreads();
  }
  if (threadIdx.x == 0)
    out[(size_t)NTOK * DIM + NTOK] =
        (float)(0.25 * red[0] / (double)((size_t)NTOK * DIM));
}

// ======================= R3 fallback path (ws too small) ==================
#define NCHUNK 8
#define CHUNK 1024
#define TT 128
#define CT 128
#define DC 32

__global__ __launch_bounds__(256)
void vq_argmin_kernel(const float* __restrict__ z, const float* __restrict__ cb,
                      const float* __restrict__ An, const float* __restrict__ Cn,
                      float* __restrict__ pv, int* __restrict__ pk) {
  __shared__ float zs[DC * TT];
  __shared__ float cs[DC * CT];
  const int tid = threadIdx.x;
  const int tx = tid & 15, ty = tid >> 4;
  const int chunk = blockIdx.x & 7;
  const int tile = blockIdx.x >> 3;
  const int base_t = tile * TT;
  const int base_k = chunk * CHUNK;
  float Areg[8];
#pragma unroll
  for (int i = 0; i < 8; ++i) Areg[i] = An[base_t + ty * 8 + i];
  float bestv[8]; int bestk[8];
#pragma unroll
  for (int i = 0; i < 8; ++i) { bestv[i] = INFINITY; bestk[i] = 0; }
  for (int st = 0; st < CHUNK / CT; ++st) {
    const int kb0 = base_k + st * CT;
    float acc[8][8];
#pragma unroll
    for (int i = 0; i < 8; ++i)
#pragma unroll
      for (int j = 0; j < 8; ++j) acc[i][j] = 0.f;
    for (int dc = 0; dc < DIM / DC; ++dc) {
      __syncthreads();
#pragma unroll
      for (int li = tid; li < DC * TT / 4; li += 256) {
        const int row = li >> 3;
        const int dv = li & 7;
        const int ibase = dv * 4 * 128 + (row ^ (dv << 2) ^ ((row & 32) >> 3));
        float4 v = *reinterpret_cast<const float4*>(
            &z[(size_t)(base_t + row) * DIM + dc * DC + dv * 4]);
        zs[ibase] = v.x; zs[ibase + 128] = v.y;
        zs[ibase + 256] = v.z; zs[ibase + 384] = v.w;
        float4 c = *reinterpret_cast<const float4*>(
            &cb[(size_t)(kb0 + row) * DIM + dc * DC + dv * 4]);
        cs[ibase] = c.x; cs[ibase + 128] = c.y;
        cs[ibase + 256] = c.z; cs[ibase + 384] = c.w;
      }
      __syncthreads();
#pragma unroll
      for (int dd = 0; dd < DC / 4; ++dd) {
        const int s1 = dd << 2;
        const float* zp0 = &zs[dd * 4 * 128 + ((ty * 8) ^ s1 ^ (ty & 4))];
        const float* zp1 = &zs[dd * 4 * 128 + ((ty * 8 + 4) ^ s1 ^ (ty & 4))];
        const float* cp0 = &cs[dd * 4 * 128 + ((tx * 8) ^ s1 ^ (tx & 4))];
        const float* cp1 = &cs[dd * 4 * 128 + ((tx * 8 + 4) ^ s1 ^ (tx & 4))];
#pragma unroll
        for (int q = 0; q < 4; ++q) {
          const float4 za  = *reinterpret_cast<const float4*>(zp0 + q * 128);
          const float4 zb  = *reinterpret_cast<const float4*>(zp1 + q * 128);
          const float4 ca  = *reinterpret_cast<const float4*>(cp0 + q * 128);
          const float4 cbv = *reinterpret_cast<const float4*>(cp1 + q * 128);
          const float zv[8] = {za.x, za.y, za.z, za.w, zb.x, zb.y, zb.z, zb.w};
          const float cv[8] = {ca.x, ca.y, ca.z, ca.w, cbv.x, cbv.y, cbv.z, cbv.w};
#pragma unroll
          for (int i = 0; i < 8; ++i)
#pragma unroll
            for (int j = 0; j < 8; ++j)
              acc[i][j] = fmaf(zv[i], cv[j], acc[i][j]);
        }
      }
    }
#pragma unroll
    for (int j = 0; j < 8; ++j) {
      const int klocal = st * CT + tx * 8 + j;
      const float Ck = Cn[base_k + klocal];
#pragma unroll
      for (int i = 0; i < 8; ++i) {
        float p2 = __fmul_rn(2.0f, acc[i][j]);
        float t1 = __fsub_rn(Areg[i], p2);
        float t  = __fadd_rn(t1, Ck);
        if (t < bestv[i]) { bestv[i] = t; bestk[i] = klocal; }
      }
    }
  }
  __syncthreads();
  float (*mv)[16] = reinterpret_cast<float(*)[16]>(zs);
  int   (*mk)[16] = reinterpret_cast<int(*)[16]>(zs + TT * 16);
#pragma unroll
  for (int i = 0; i < 8; ++i) { mv[ty * 8 + i][tx] = bestv[i]; mk[ty * 8 + i][tx] = bestk[i]; }
  __syncthreads();
  if (tid < TT) {
    float bv = mv[tid][0]; int bk = mk[tid][0];
#pragma unroll
    for (int x = 1; x < 16; ++x) {
      float v = mv[tid][x]; int k = mk[tid][x];
      if (v < bv || (v == bv && k < bk)) { bv = v; bk = k; }
    }
    size_t idx = (size_t)(base_t + tid) * NCHUNK + chunk;
    pv[idx] = bv;
    pk[idx] = base_k + bk;
  }
}

__global__ __launch_bounds__(256)
void vq_finalize(const float* __restrict__ z, const float* __restrict__ cb,
                 const float* __restrict__ pv, const int* __restrict__ pk,
                 float* __restrict__ out, double* __restrict__ loss_acc) {
  const int n = blockIdx.x * 4 + (threadIdx.x >> 6);
  const int lane = threadIdx.x & 63;
  float bv = INFINITY; int bk = 0;
#pragma unroll
  for (int c = 0; c < NCHUNK; ++c) {
    float v = pv[(size_t)n * NCHUNK + c];
    int k = pk[(size_t)n * NCHUNK + c];
    if (v < bv || (v == bv && k < bk)) { bv = v; bk = k; }
  }
  const float4 c4 = *reinterpret_cast<const float4*>(&cb[(size_t)bk * DIM + lane * 4]);
  const float4 z4 = *reinterpret_cast<const float4*>(&z[(size_t)n * DIM + lane * 4]);
  *reinterpret_cast<float4*>(&out[(size_t)n * DIM + lane * 4]) = c4;
  float dx = __fsub_rn(c4.x, z4.x), dy = __fsub_rn(c4.y, z4.y);
  float dz = __fsub_rn(c4.z, z4.z), dw = __fsub_rn(c4.w, z4.w);
  double s = (double)dx * dx + (double)dy * dy + (double)dz * dz + (double)dw * dw;
#pragma unroll
  for (int off = 32; off > 0; off >>= 1) s += __shfl_down(s, off);
  if (lane == 0) {
    out[(size_t)NTOK * DIM + n] = (float)bk;
    atomicAdd(loss_acc, s);
  }
}

__global__ void vq_loss_write_fb(const double* __restrict__ loss_acc, float* __restrict__ out) {
  out[(size_t)NTOK * DIM + NTOK] = (float)(0.25 * (*loss_acc) / (double)((size_t)NTOK * DIM));
}

// ==========================================================================
extern "C" void kernel_launch(void* const* d_in, const int* in_sizes, int n_in,
                              void* d_out, int out_size, void* d_ws, size_t ws_size,
                              hipStream_t stream) {
  const float* z  = (const float*)d_in[0];
  const float* cb = (const float*)d_in[1];
  float* out = (float*)d_out;
  char* ws = (char*)d_ws;

  if (ws_size >= WS_NEED) {
    float*     An   = (float*)(ws + OFF_AN);
    float*     Cn   = (float*)(ws + OFF_CN);
    int*       ids  = (int*)(ws + OFF_IDS);
    int*       rcnt = (int*)(ws + OFF_RCNT);
    int*       rlist= (int*)(ws + OFF_RLIST);
    double*    part = (double*)(ws + OFF_PART);
    u64*       pk1  = (u64*)(ws + OFF_PK1);
    float*     pv2  = (float*)(ws + OFF_PV2);
    _Float16*  z16  = (_Float16*)(ws + OFF_Z16);
    _Float16*  c16  = (_Float16*)(ws + OFF_CB16);
    u64*       rmin = pk1;   // first 256 KB of pk1 reused after detect

    hipMemsetAsync(rcnt, 0, 128, stream);
    vq_prep<<<1440, 256, 0, stream>>>(z, cb, An, Cn, z16, c16);
    vq_mfma_top2<<<4096, 256, 0, stream>>>(z16, c16, An, Cn, pk1, pv2);
    vq_detect<<<NTOK / 256, 256, 0, stream>>>(pk1, pv2, ids, rcnt, rlist);
    hipMemsetAsync(rmin, 0xFF, (size_t)NTOK * sizeof(u64), stream);  // after detect
    vq_rescue2<<<2048, 256, 0, stream>>>(z, cb, An, Cn, rcnt, rlist, rmin);
    vq_rescue_apply<<<32, 256, 0, stream>>>(rcnt, rlist, rmin, ids);
    vq_finalize_ids<<<NTOK / 16, 256, 0, stream>>>(z, cb, ids, out, part);
    vq_loss_write<<<1, 256, 0, stream>>>(part, out);
  } else {
    // R3 fallback (needs ~2.26 MB)
    float*  An = (float*)(ws);
    float*  Cn = (float*)(ws + 131072);
    float*  pv = (float*)(ws + 163840);
    int*    pk = (int*)(ws + 1212416);
    double* loss = (double*)(ws + 2260992);
    hipMemsetAsync(loss, 0, sizeof(double), stream);
    rownorm256_np<<<NTOK / 256, 256, 0, stream>>>(z, An, NTOK);
    rownorm256_np<<<KCB / 256, 256, 0, stream>>>(cb, Cn, KCB);
    vq_argmin_kernel<<<(NTOK / TT) * NCHUNK, 256, 0, stream>>>(z, cb, An, Cn, pv, pk);
    vq_finalize<<<NTOK / 4, 256, 0, stream>>>(z, cb, pv, pk, out, loss);
    vq_loss_write_fb<<<1, 1, 0, stream>>>(loss, out);
  }
}